// Round 7
// baseline (294.302 us; speedup 1.0000x reference)
//
#include <hip/hip_runtime.h>
#include <hip/hip_fp16.h>
#include <math.h>

#define NEG_SLOPE 0.2f
#define BKT_SHIFT 8
#define BKT_NODES (1 << BKT_SHIFT)       // 256 nodes per bucket
#define BKT_CAP 512                      // >= B = ceil(N/256) = 391
#define BKT_FCAP 6144                    // fixed edge capacity per bucket (avg 4092)
#define BKT_SHARD (BKT_FCAP / 4)         // 1536 per shard (expected ~1023, 16-sigma margin)
#define P1_CHUNK 1024                    // 1563 blocks = 6.1/CU (was 391 blocks = 1.5/CU)
#define SEG_SHIFT 14                     // src segments of 16384 nodes (2.1 MB of H rows, fits 4MB L2)
#define NSEG 8

typedef _Float16 f16x8 __attribute__((ext_vector_type(8)));
typedef float    f32x4 __attribute__((ext_vector_type(4)));
union FU  { uint4 u; f16x8 f; };
union H2U { __half2 h; unsigned u; };

__device__ __forceinline__ float lrelu(float x){ return fmaxf(x, NEG_SLOPE * x); }
__device__ __forceinline__ float elu_fast(float x){
  float t = __expf(fminf(x, 0.f)) - 1.f;
  return x > 0.f ? x : t;
}

// ---------------- bucketed CSR build (single-pass, fixed-cap buckets) ----------------
// bucket b = dst >> 8. pairs packed: (dst&255)<<17 | src  (src < 2^17)
// bktCur sharded x4 by blockIdx&3 to cut same-address atomic serialization.
// Block 0 additionally packs the W fragments (saves a dispatch).

__global__ __launch_bounds__(256) void k_p1(const int* __restrict__ src, const int* __restrict__ dst,
                                            int E, int B, int* __restrict__ bktCur,
                                            unsigned* __restrict__ pairs,
                                            const float* __restrict__ W1, const float* __restrict__ W2,
                                            uint4* __restrict__ W1f, uint4* __restrict__ W2f){
  __shared__ int h[BKT_CAP], base[BKT_CAP], cur[BKT_CAP];
  int tid = threadIdx.x;
  if (blockIdx.x == 0){
    // W1 fragments: fs = t*4+s (t,s in 0..3); W2: fs = t*2+s (t 0..3, s 0..1)
    for (int idx = tid; idx < 16 * 64; idx += 256){
      int lane = idx & 63, fs = idx >> 6;
      int t = fs >> 2, s = fs & 3;
      int m = lane & 15, quad = lane >> 4;
      f16x8 v;
      #pragma unroll
      for (int j = 0; j < 8; ++j)
        v[j] = (_Float16)W1[(s * 32 + quad * 8 + j) * 64 + t * 16 + m];
      FU fu; fu.f = v;
      W1f[fs * 64 + lane] = fu.u;
    }
    for (int idx = tid; idx < 8 * 64; idx += 256){
      int lane = idx & 63, fs = idx >> 6;
      int t = fs >> 1, s = fs & 1;
      int m = lane & 15, quad = lane >> 4;
      f16x8 v;
      #pragma unroll
      for (int j = 0; j < 8; ++j)
        v[j] = (_Float16)W2[(s * 32 + quad * 8 + j) * 64 + t * 16 + m];
      FU fu; fu.f = v;
      W2f[fs * 64 + lane] = fu.u;
    }
  }
  for (int i = tid; i < BKT_CAP; i += 256){ h[i] = 0; cur[i] = 0; }
  __syncthreads();
  int beg = blockIdx.x * P1_CHUNK;
  int end = min(beg + P1_CHUNK, E);
  int shard = blockIdx.x & 3;
  int m4 = (end - beg) >> 2;
  const int4* d4 = (const int4*)(dst + beg);
  const int4* s4 = (const int4*)(src + beg);
  for (int i = tid; i < m4; i += 256){
    int4 d = d4[i];
    atomicAdd(&h[d.x >> BKT_SHIFT], 1); atomicAdd(&h[d.y >> BKT_SHIFT], 1);
    atomicAdd(&h[d.z >> BKT_SHIFT], 1); atomicAdd(&h[d.w >> BKT_SHIFT], 1);
  }
  for (int i = beg + (m4 << 2) + tid; i < end; i += 256)
    atomicAdd(&h[dst[i] >> BKT_SHIFT], 1);
  __syncthreads();
  for (int i = tid; i < B; i += 256)
    if (h[i]) base[i] = i * BKT_FCAP + shard * BKT_SHARD + atomicAdd(&bktCur[i * 4 + shard], h[i]);
  __syncthreads();
  for (int i = tid; i < m4; i += 256){
    int4 d = d4[i]; int4 s = s4[i];
    int b0 = d.x >> BKT_SHIFT, b1 = d.y >> BKT_SHIFT, b2 = d.z >> BKT_SHIFT, b3 = d.w >> BKT_SHIFT;
    int p0 = base[b0] + atomicAdd(&cur[b0], 1);
    pairs[p0] = ((unsigned)(d.x & (BKT_NODES-1)) << 17) | (unsigned)s.x;
    int p1 = base[b1] + atomicAdd(&cur[b1], 1);
    pairs[p1] = ((unsigned)(d.y & (BKT_NODES-1)) << 17) | (unsigned)s.y;
    int p2 = base[b2] + atomicAdd(&cur[b2], 1);
    pairs[p2] = ((unsigned)(d.z & (BKT_NODES-1)) << 17) | (unsigned)s.z;
    int p3 = base[b3] + atomicAdd(&cur[b3], 1);
    pairs[p3] = ((unsigned)(d.w & (BKT_NODES-1)) << 17) | (unsigned)s.w;
  }
  for (int i = beg + (m4 << 2) + tid; i < end; i += 256){
    int d = dst[i], s = src[i];
    int b = d >> BKT_SHIFT;
    int p = base[b] + atomicAdd(&cur[b], 1);
    pairs[p] = ((unsigned)(d & (BKT_NODES-1)) << 17) | (unsigned)s;
  }
}

// one block (256 thr) per bucket: LDS hist -> scan -> offs2 (int2{beg,end}) + padded col.
// Placement is done in NSEG passes over the bucket's pairs (L2-resident, 24KB) so each
// node's edge list is ordered by src segment -> agg gathers concentrate in a 2.1MB
// window that fits every XCD L2 (kills the 7x H-table re-fetch from HBM/L3).
__device__ __forceinline__ void p2_body(const unsigned* __restrict__ pairs,
                                        const int* __restrict__ bktCur,
                                        int N, int2* __restrict__ offs2, int* __restrict__ col, int b){
  __shared__ int sc[BKT_NODES], cu[BKT_NODES];
  int tid = threadIdx.x;
  int nbase = b << BKT_SHIFT;
  int bs = b * BKT_FCAP;
  int cnt0 = bktCur[b * 4 + 0], cnt1 = bktCur[b * 4 + 1];
  int cnt2 = bktCur[b * 4 + 2], cnt3 = bktCur[b * 4 + 3];
  int cnts[4] = {cnt0, cnt1, cnt2, cnt3};
  sc[tid] = 0;
  __syncthreads();
  #pragma unroll
  for (int s = 0; s < 4; ++s){
    int ss_ = bs + s * BKT_SHARD;
    int se_ = ss_ + cnts[s];
    for (int i = ss_ + tid; i < se_; i += 256)
      atomicAdd(&sc[pairs[i] >> 17], 1);
  }
  __syncthreads();
  int v = sc[tid];
  for (int o = 1; o < 256; o <<= 1){
    int x = (tid >= o) ? sc[tid - o] : 0;
    __syncthreads();
    sc[tid] += x;
    __syncthreads();
  }
  int ex = sc[tid] - v;
  cu[tid] = bs + ex;
  if (nbase + tid < N) offs2[nbase + tid] = make_int2(bs + ex, bs + ex + v);
  __syncthreads();
  // segment-ordered placement: pass seg places only edges with src>>SEG_SHIFT == seg;
  // cursor continues across passes -> per-node lists end up segment-sorted.
  for (int seg = 0; seg < NSEG; ++seg){
    #pragma unroll
    for (int s = 0; s < 4; ++s){
      int ss_ = bs + s * BKT_SHARD;
      int se_ = ss_ + cnts[s];
      for (int i = ss_ + tid; i < se_; i += 256){
        unsigned pr = pairs[i];
        unsigned srcv = pr & 0x1FFFFu;
        if ((int)(srcv >> SEG_SHIFT) == seg){
          int p = atomicAdd(&cu[pr >> 17], 1);
          col[p] = (int)srcv;
        }
      }
    }
    __syncthreads();
  }
}

// ---------------- MFMA GEMM 1 body: H(fp16)[n,64] = X(fp32)[n,128] @ W1, + logits --------
__device__ __forceinline__ void mg1_body(
    const float* __restrict__ X, const uint4* __restrict__ Wf,
    const float* __restrict__ a_src, const float* __restrict__ a_dst,
    uint2* __restrict__ H, float* __restrict__ as_, float* __restrict__ ad_, int n, int bb)
{
  int lane = threadIdx.x & 63, wv = threadIdx.x >> 6;
  int quad = lane >> 4, nn = lane & 15;
  int rowb = bb * 64 + wv * 16;
  int row = rowb + nn;
  bool ok = row < n;
  int rowc = ok ? row : n - 1;

  f16x8 af[4][4];
  #pragma unroll
  for (int t = 0; t < 4; ++t)
    #pragma unroll
    for (int s = 0; s < 4; ++s){
      FU fu; fu.u = Wf[(t * 4 + s) * 64 + lane];
      af[t][s] = fu.f;
    }

  const float4* Xr = (const float4*)(X + (size_t)rowc * 128);
  float4 xb[4][2];
  #pragma unroll
  for (int s = 0; s < 4; ++s){
    xb[s][0] = Xr[s * 8 + quad * 2];
    xb[s][1] = Xr[s * 8 + quad * 2 + 1];
  }

  f32x4 acc[4] = {};
  #pragma unroll
  for (int s = 0; s < 4; ++s){
    f16x8 bf;
    bf[0] = (_Float16)xb[s][0].x; bf[1] = (_Float16)xb[s][0].y;
    bf[2] = (_Float16)xb[s][0].z; bf[3] = (_Float16)xb[s][0].w;
    bf[4] = (_Float16)xb[s][1].x; bf[5] = (_Float16)xb[s][1].y;
    bf[6] = (_Float16)xb[s][1].z; bf[7] = (_Float16)xb[s][1].w;
    #pragma unroll
    for (int t = 0; t < 4; ++t)
      acc[t] = __builtin_amdgcn_mfma_f32_16x16x32_f16(af[t][s], bf, acc[t], 0, 0, 0);
  }

  if (ok){
    #pragma unroll
    for (int t = 0; t < 4; ++t){
      H2U p0, p1;
      p0.h = __floats2half2_rn(acc[t][0], acc[t][1]);
      p1.h = __floats2half2_rn(acc[t][2], acc[t][3]);
      H[(size_t)row * 16 + t * 4 + quad] = make_uint2(p0.u, p1.u);
    }
  }
  float sl = 0.f, dl = 0.f;
  #pragma unroll
  for (int t = 0; t < 4; ++t){
    float4 a4 = ((const float4*)a_src)[t * 4 + quad];
    float4 d4 = ((const float4*)a_dst)[t * 4 + quad];
    sl += acc[t][0] * a4.x + acc[t][1] * a4.y + acc[t][2] * a4.z + acc[t][3] * a4.w;
    dl += acc[t][0] * d4.x + acc[t][1] * d4.y + acc[t][2] * d4.z + acc[t][3] * d4.w;
  }
  sl += __shfl_xor(sl, 16, 64); sl += __shfl_xor(sl, 32, 64);
  dl += __shfl_xor(dl, 16, 64); dl += __shfl_xor(dl, 32, 64);
  if (lane < 16 && ok){ as_[row] = sl; ad_[row] = dl; }
}

// fused: blocks [0, p2B) run CSR finalize, blocks [p2B, ...) run GEMM1.
// Independent: p2 reads pairs (aliased to h2), mgemm1 writes h1 — disjoint.
__global__ __launch_bounds__(256) void k_fused(
    const unsigned* __restrict__ pairs, const int* __restrict__ bktCur,
    int N, int2* __restrict__ offs2, int* __restrict__ col, int p2B,
    const float* __restrict__ X, const uint4* __restrict__ Wf,
    const float* __restrict__ a_src, const float* __restrict__ a_dst,
    uint2* __restrict__ H, float* __restrict__ as_, float* __restrict__ ad_)
{
  if ((int)blockIdx.x < p2B)
    p2_body(pairs, bktCur, N, offs2, col, blockIdx.x);
  else
    mg1_body(X, Wf, a_src, a_dst, H, as_, ad_, N, blockIdx.x - p2B);
}

// ---------------- attention aggregation core (round-0 proven: 8 nodes/wave, x4 unroll) --
#define FMA8(e, hv) { const __half2* hp = (const __half2*)&(hv);               \
  a[0]=fmaf(e, __half2float(hp[0].x), a[0]); a[1]=fmaf(e, __half2float(hp[0].y), a[1]); \
  a[2]=fmaf(e, __half2float(hp[1].x), a[2]); a[3]=fmaf(e, __half2float(hp[1].y), a[3]); \
  a[4]=fmaf(e, __half2float(hp[2].x), a[4]); a[5]=fmaf(e, __half2float(hp[2].y), a[5]); \
  a[6]=fmaf(e, __half2float(hp[3].x), a[6]); a[7]=fmaf(e, __half2float(hp[3].y), a[7]); }

__device__ __forceinline__ void agg_core(
    const int2* __restrict__ offs2, const int* __restrict__ col,
    const uint4* __restrict__ H4, const float* __restrict__ as_, const float* __restrict__ ad_,
    int node, int c8, float& denom, float a[8])
{
  int2 be2 = offs2[node];
  int beg = be2.x, d = be2.y - be2.x;
  int maxd = d;
  maxd = max(maxd, __shfl_xor(maxd, 8, 64));
  maxd = max(maxd, __shfl_xor(maxd, 16, 64));
  maxd = max(maxd, __shfl_xor(maxd, 32, 64));
  float adv = ad_[node];
  float exs = __expf(lrelu(as_[node] + adv));
  uint4 hself = H4[(size_t)node * 8 + c8];
  denom = exs;
  { const __half2* hp = (const __half2*)&hself;
    #pragma unroll
    for (int i = 0; i < 4; ++i){
      a[2*i]   = exs * __half2float(hp[i].x);
      a[2*i+1] = exs * __half2float(hp[i].y);
    } }
  for (int j = 0; j < maxd; j += 4){
    int ss[4]; float asv[4]; uint4 hv[4];
    #pragma unroll
    for (int u = 0; u < 4; ++u) ss[u] = (j + u < d) ? col[beg + j + u] : 0;
    #pragma unroll
    for (int u = 0; u < 4; ++u) asv[u] = as_[ss[u]];
    #pragma unroll
    for (int u = 0; u < 4; ++u) hv[u] = H4[(size_t)ss[u] * 8 + c8];
    #pragma unroll
    for (int u = 0; u < 4; ++u){
      float e = (j + u < d) ? __expf(lrelu(asv[u] + adv)) : 0.f;
      denom += e;
      FMA8(e, hv[u])
    }
  }
}

// ---------------- fused agg1 + GEMM2: one block = 32 nodes ----------------
__global__ __launch_bounds__(256) void k_agg1f(
    const int2* __restrict__ offs2, const int* __restrict__ col,
    const uint4* __restrict__ H4, const float* __restrict__ as_, const float* __restrict__ ad_,
    const float* __restrict__ bias, const uint4* __restrict__ W2f,
    const float* __restrict__ a_src2, const float* __restrict__ a_dst2,
    uint2* __restrict__ H2out, float* __restrict__ as2_, float* __restrict__ ad2_, int n)
{
  // 72 halves/row (36 uints, 144 B stride): breaks the 128 B power-of-2 bank pattern
  __shared__ unsigned uhl[32][36];
  int lane = threadIdx.x & 63, w = threadIdx.x >> 6;
  int m = lane >> 3, c8 = lane & 7;
  int node0 = blockIdx.x * 32 + w * 8 + m;
  bool ok = node0 < n;
  int node = ok ? node0 : n - 1;
  float denom; float a[8];
  agg_core(offs2, col, H4, as_, ad_, node, c8, denom, a);
  float inv = 1.f / denom;
  float4 b0 = *(const float4*)&bias[8 * c8];
  float4 b1 = *(const float4*)&bias[8 * c8 + 4];
  float bb[8] = {b0.x, b0.y, b0.z, b0.w, b1.x, b1.y, b1.z, b1.w};
  int ln = w * 8 + m;
  #pragma unroll
  for (int i = 0; i < 4; ++i){
    float v0 = elu_fast(fmaf(a[2*i],   inv, bb[2*i]));
    float v1 = elu_fast(fmaf(a[2*i+1], inv, bb[2*i+1]));
    __half2 h = __floats2half2_rn(v0, v1);
    uhl[ln][c8 * 4 + i] = *(unsigned*)&h;
  }
  __syncthreads();

  // -------- phase 2: 32-row GEMM on waves 0-1 (rows w*16+nn) --------
  if (w < 2){
    int quad = lane >> 4, nn = lane & 15;
    int lrow = w * 16 + nn;
    int row = blockIdx.x * 32 + lrow;
    bool ok2 = row < n;

    f16x8 af[4][2];
    #pragma unroll
    for (int t = 0; t < 4; ++t)
      #pragma unroll
      for (int s = 0; s < 2; ++s){
        FU fu; fu.u = W2f[(t * 2 + s) * 64 + lane];
        af[t][s] = fu.f;
      }

    f16x8 bf[2];
    #pragma unroll
    for (int s = 0; s < 2; ++s){
      FU fu; fu.u = ((const uint4*)&uhl[lrow][0])[s * 4 + quad];
      bf[s] = fu.f;
    }

    f32x4 acc[4] = {};
    #pragma unroll
    for (int s = 0; s < 2; ++s)
      #pragma unroll
      for (int t = 0; t < 4; ++t)
        acc[t] = __builtin_amdgcn_mfma_f32_16x16x32_f16(af[t][s], bf[s], acc[t], 0, 0, 0);

    if (ok2){
      #pragma unroll
      for (int t = 0; t < 4; ++t){
        H2U p0, p1;
        p0.h = __floats2half2_rn(acc[t][0], acc[t][1]);
        p1.h = __floats2half2_rn(acc[t][2], acc[t][3]);
        H2out[(size_t)row * 16 + t * 4 + quad] = make_uint2(p0.u, p1.u);
      }
    }
    float sl = 0.f, dl = 0.f;
    #pragma unroll
    for (int t = 0; t < 4; ++t){
      float4 a4 = ((const float4*)a_src2)[t * 4 + quad];
      float4 d4 = ((const float4*)a_dst2)[t * 4 + quad];
      sl += acc[t][0] * a4.x + acc[t][1] * a4.y + acc[t][2] * a4.z + acc[t][3] * a4.w;
      dl += acc[t][0] * d4.x + acc[t][1] * d4.y + acc[t][2] * d4.z + acc[t][3] * d4.w;
    }
    sl += __shfl_xor(sl, 16, 64); sl += __shfl_xor(sl, 32, 64);
    dl += __shfl_xor(dl, 16, 64); dl += __shfl_xor(dl, 32, 64);
    if (lane < 16 && ok2){ as2_[row] = sl; ad2_[row] = dl; }
  }
}

// ---------------- agg2: layer-2 aggregation + output head (round-0 proven) ----------------
__global__ __launch_bounds__(256) void k_agg2(
    const int2* __restrict__ offs2, const int* __restrict__ col,
    const uint4* __restrict__ H4, const float* __restrict__ as_, const float* __restrict__ ad_,
    const float* __restrict__ bias, const float* __restrict__ Wout, const float* __restrict__ bout,
    float* __restrict__ out, int n)
{
  int lane = threadIdx.x & 63, w = threadIdx.x >> 6;
  int m = lane >> 3, c8 = lane & 7;
  int node0 = blockIdx.x * 32 + w * 8 + m;
  bool ok = node0 < n;
  int node = ok ? node0 : n - 1;
  float denom; float a[8];
  agg_core(offs2, col, H4, as_, ad_, node, c8, denom, a);
  float inv = 1.f / denom;
  float4 b0 = *(const float4*)&bias[8 * c8];
  float4 b1 = *(const float4*)&bias[8 * c8 + 4];
  float4 w0 = *(const float4*)&Wout[8 * c8];
  float4 w1 = *(const float4*)&Wout[8 * c8 + 4];
  float bb[8] = {b0.x, b0.y, b0.z, b0.w, b1.x, b1.y, b1.z, b1.w};
  float ww[8] = {w0.x, w0.y, w0.z, w0.w, w1.x, w1.y, w1.z, w1.w};
  float p = 0.f;
  #pragma unroll
  for (int i = 0; i < 8; ++i)
    p += elu_fast(fmaf(a[i], inv, bb[i])) * ww[i];
  p += __shfl_xor(p, 1, 64); p += __shfl_xor(p, 2, 64); p += __shfl_xor(p, 4, 64);
  if (c8 == 0 && ok) out[node] = p + bout[0];
}

// ---------------- launch ----------------
extern "C" void kernel_launch(void* const* d_in, const int* in_sizes, int n_in,
                              void* d_out, int out_size, void* d_ws, size_t ws_size,
                              hipStream_t stream)
{
  const float* x    = (const float*)d_in[0];
  const int*   ei   = (const int*)d_in[1];   // int32 [2, E] flat
  const float* W1   = (const float*)d_in[2];
  const float* as1w = (const float*)d_in[3];
  const float* ad1w = (const float*)d_in[4];
  const float* b1   = (const float*)d_in[5];
  const float* W2   = (const float*)d_in[6];
  const float* as2w = (const float*)d_in[7];
  const float* ad2w = (const float*)d_in[8];
  const float* b2   = (const float*)d_in[9];
  const float* Wout = (const float*)d_in[10];
  const float* bout = (const float*)d_in[11];
  float* out = (float*)d_out;

  const int N = in_sizes[0] / 128;
  const int E = in_sizes[1] / 2;
  const int* srcA = ei;
  const int* dstA = ei + E;
  const int B = (N + BKT_NODES - 1) >> BKT_SHIFT;   // 391 (<= BKT_CAP); src < 2^17 required

  char* p = (char*)d_ws;
  auto alloc = [&](size_t bytes){ char* r = p; p += (bytes + 255) & ~255ull; return r; };
  int*   bktCur = (int*)alloc(BKT_CAP * 4 * 4);              // x4 shards
  int2*  offs2  = (int2*)alloc((size_t)N * 8);
  int*   col    = (int*)alloc((size_t)B * BKT_FCAP * 4);     // padded CSR col (9.6 MB)
  float* vas1 = (float*)alloc((size_t)N * 4);
  float* vad1 = (float*)alloc((size_t)N * 4);
  float* vas2 = (float*)alloc((size_t)N * 4);
  float* vad2 = (float*)alloc((size_t)N * 4);
  uint4* w1f  = (uint4*)alloc(16 * 64 * 16);
  uint4* w2f  = (uint4*)alloc(8 * 64 * 16);
  uint2* h1   = (uint2*)alloc((size_t)N * 64 * 2);   // fp16 [N,64] (layer-1 features)
  uint2* h2   = (uint2*)alloc((size_t)N * 64 * 2);   // fp16 [N,64] (layer-2 features)
  // pairs aliases h2 (NOT h1): p2 reads pairs while mgemm1 writes h1 concurrently;
  // h2 is first written by k_agg1f, after pairs is dead.
  unsigned* pairs = (unsigned*)h2;

  hipMemsetAsync(bktCur, 0, BKT_CAP * 4 * 4, stream);

  int nchunk = (E + P1_CHUNK - 1) / P1_CHUNK;
  k_p1<<<nchunk, 256, 0, stream>>>(srcA, dstA, E, B, bktCur, pairs, W1, W2, w1f, w2f);

  int gblocks = (N + 63) / 64;
  int ablocks = (N + 31) / 32;
  // p2 (CSR finalize) || mgemm1 (layer-1 GEMM) — independent, complementary pipes
  k_fused<<<B + gblocks, 256, 0, stream>>>(pairs, bktCur, N, offs2, col, B,
                                           x, w1f, as1w, ad1w, h1, vas1, vad1);
  k_agg1f <<<ablocks, 256, 0, stream>>>(offs2, col, (const uint4*)h1, vas1, vad1, b1,
                                        w2f, as2w, ad2w, h2, vas2, vad2, N);
  k_agg2  <<<ablocks, 256, 0, stream>>>(offs2, col, (const uint4*)h2, vas2, vad2, b2, Wout, bout, out, N);
}

// Round 8
// 222.627 us; speedup vs baseline: 1.3219x; 1.3219x over previous
//
#include <hip/hip_runtime.h>
#include <hip/hip_fp16.h>
#include <math.h>

#define NEG_SLOPE 0.2f
#define BKT_SHIFT 8
#define BKT_NODES (1 << BKT_SHIFT)       // 256 nodes per bucket
#define BKT_FCAP 6144                    // fixed col capacity per bucket (avg 4092, 32-sigma)
#define P1_CHUNK 4096                    // edges per p1 block (block-owned region)

typedef _Float16 f16x8 __attribute__((ext_vector_type(8)));
typedef float    f32x4 __attribute__((ext_vector_type(4)));
union FU  { uint4 u; f16x8 f; };
union H2U { __half2 h; unsigned u; };

__device__ __forceinline__ float lrelu(float x){ return fmaxf(x, NEG_SLOPE * x); }
__device__ __forceinline__ float elu_fast(float x){
  float t = __expf(fminf(x, 0.f)) - 1.f;
  return x > 0.f ? x : t;
}

// ---------------- p1: block-owned counting sort of 4096 edges ----------------
// Block i owns pairs[i*4096 .. i*4096+cnt) grouped by bucket (b = dst>>8) and writes
// offsT[i*(B+1)+b] = exclusive start of bucket b's run (offsT[i*(B+1)+B] = cnt).
// No global atomics, no memset, fully coalesced writes. 512 threads for TLP.
// Block 0 additionally packs the W fragments.
__global__ __launch_bounds__(512) void k_p1(const int* __restrict__ src, const int* __restrict__ dst,
                                            int E, int B,
                                            unsigned* __restrict__ pairs, int* __restrict__ offsT,
                                            const float* __restrict__ W1, const float* __restrict__ W2,
                                            uint4* __restrict__ W1f, uint4* __restrict__ W2f){
  __shared__ int h[512], cur[512];
  __shared__ unsigned stage[P1_CHUNK];
  int tid = threadIdx.x;
  if (blockIdx.x == 0){
    // W1 fragments: fs = t*4+s (t,s in 0..3); W2: fs = t*2+s (t 0..3, s 0..1)
    for (int idx = tid; idx < 16 * 64; idx += 512){
      int lane = idx & 63, fs = idx >> 6;
      int t = fs >> 2, s = fs & 3;
      int m = lane & 15, quad = lane >> 4;
      f16x8 v;
      #pragma unroll
      for (int j = 0; j < 8; ++j)
        v[j] = (_Float16)W1[(s * 32 + quad * 8 + j) * 64 + t * 16 + m];
      FU fu; fu.f = v;
      W1f[fs * 64 + lane] = fu.u;
    }
    for (int idx = tid; idx < 8 * 64; idx += 512){
      int lane = idx & 63, fs = idx >> 6;
      int t = fs >> 1, s = fs & 1;
      int m = lane & 15, quad = lane >> 4;
      f16x8 v;
      #pragma unroll
      for (int j = 0; j < 8; ++j)
        v[j] = (_Float16)W2[(s * 32 + quad * 8 + j) * 64 + t * 16 + m];
      FU fu; fu.f = v;
      W2f[fs * 64 + lane] = fu.u;
    }
  }
  h[tid] = 0;
  __syncthreads();
  int beg = blockIdx.x * P1_CHUNK;
  int end = min(beg + P1_CHUNK, E);
  int cnt = end - beg;
  int m4 = cnt >> 2;
  const int4* d4 = (const int4*)(dst + beg);
  const int4* s4 = (const int4*)(src + beg);
  for (int i = tid; i < m4; i += 512){
    int4 d = d4[i];
    atomicAdd(&h[d.x >> BKT_SHIFT], 1); atomicAdd(&h[d.y >> BKT_SHIFT], 1);
    atomicAdd(&h[d.z >> BKT_SHIFT], 1); atomicAdd(&h[d.w >> BKT_SHIFT], 1);
  }
  for (int i = (m4 << 2) + tid; i < cnt; i += 512)
    atomicAdd(&h[dst[beg + i] >> BKT_SHIFT], 1);
  __syncthreads();
  // inclusive Hillis-Steele scan over h[0..512)
  int v = h[tid];
  for (int o = 1; o < 512; o <<= 1){
    int x = (tid >= o) ? h[tid - o] : 0;
    __syncthreads();
    h[tid] += x;
    __syncthreads();
  }
  int e = h[tid] - v;                    // exclusive prefix
  cur[tid] = e;
  int* orow = offsT + (size_t)blockIdx.x * (B + 1);
  if (tid <= B) orow[tid] = e;           // orow[B] = total cnt (buckets >= B empty)
  __syncthreads();
  // scatter into LDS stage, grouped by bucket
  for (int i = tid; i < m4; i += 512){
    int4 d = d4[i]; int4 s = s4[i];
    int p0 = atomicAdd(&cur[d.x >> BKT_SHIFT], 1);
    stage[p0] = ((unsigned)(d.x & (BKT_NODES-1)) << 17) | (unsigned)s.x;
    int p1 = atomicAdd(&cur[d.y >> BKT_SHIFT], 1);
    stage[p1] = ((unsigned)(d.y & (BKT_NODES-1)) << 17) | (unsigned)s.y;
    int p2 = atomicAdd(&cur[d.z >> BKT_SHIFT], 1);
    stage[p2] = ((unsigned)(d.z & (BKT_NODES-1)) << 17) | (unsigned)s.z;
    int p3 = atomicAdd(&cur[d.w >> BKT_SHIFT], 1);
    stage[p3] = ((unsigned)(d.w & (BKT_NODES-1)) << 17) | (unsigned)s.w;
  }
  for (int i = (m4 << 2) + tid; i < cnt; i += 512){
    int d = dst[beg + i], s = src[beg + i];
    int p = atomicAdd(&cur[d >> BKT_SHIFT], 1);
    stage[p] = ((unsigned)(d & (BKT_NODES-1)) << 17) | (unsigned)s;
  }
  __syncthreads();
  // coalesced writeout of the block's region
  unsigned* prow = pairs + (size_t)blockIdx.x * P1_CHUNK;
  for (int i = tid; i < cnt; i += 512) prow[i] = stage[i];
}

// ---------------- p2: per-bucket CSR finalize from block-owned runs ----------------
// Gathers bucket b's run from each of NCH chunk regions into LDS (run-length scan for
// placement), then hist -> scan -> offs2 + col exactly as before. 256 threads.
__device__ __forceinline__ void p2_body(const unsigned* __restrict__ pairs,
                                        const int* __restrict__ offsT,
                                        int NCH, int B, int N,
                                        int2* __restrict__ offs2, int* __restrict__ col, int b){
  __shared__ int sc[BKT_NODES], cu[BKT_NODES], rbase[512];
  __shared__ unsigned estage[BKT_FCAP];
  int tid = threadIdx.x;
  int nbase = b << BKT_SHIFT;
  int bs = b * BKT_FCAP;
  // run descriptors for chunks tid and tid+256
  int i0 = tid, i1 = tid + 256;
  int st0 = 0, ln0 = 0, st1 = 0, ln1 = 0;
  if (i0 < NCH){ int o = offsT[(size_t)i0 * (B + 1) + b]; st0 = o; ln0 = offsT[(size_t)i0 * (B + 1) + b + 1] - o; }
  if (i1 < NCH){ int o = offsT[(size_t)i1 * (B + 1) + b]; st1 = o; ln1 = offsT[(size_t)i1 * (B + 1) + b + 1] - o; }
  rbase[tid] = ln0; rbase[tid + 256] = ln1;
  sc[tid] = 0;
  __syncthreads();
  // inclusive scan over rbase[0..512) with 256 threads (2 lanes each, lockstep)
  for (int o = 1; o < 512; o <<= 1){
    int x0 = (tid >= o) ? rbase[tid - o] : 0;
    int x1 = rbase[tid + 256 - o];       // tid+256 >= 256 >= o always
    __syncthreads();
    rbase[tid] += x0; rbase[tid + 256] += x1;
    __syncthreads();
  }
  int tot = rbase[511];
  int r0 = rbase[tid] - ln0, r1 = rbase[tid + 256] - ln1;
  // copy runs into estage (thread-serial, ~10.5 edges/run, L2-resident source)
  for (int j = 0; j < ln0; ++j) estage[r0 + j] = pairs[(size_t)i0 * P1_CHUNK + st0 + j];
  for (int j = 0; j < ln1; ++j) estage[r1 + j] = pairs[(size_t)i1 * P1_CHUNK + st1 + j];
  __syncthreads();
  // per-node hist
  for (int i = tid; i < tot; i += 256) atomicAdd(&sc[estage[i] >> 17], 1);
  __syncthreads();
  int v = sc[tid];
  for (int o = 1; o < 256; o <<= 1){
    int x = (tid >= o) ? sc[tid - o] : 0;
    __syncthreads();
    sc[tid] += x;
    __syncthreads();
  }
  int ex = sc[tid] - v;
  cu[tid] = bs + ex;
  if (nbase + tid < N) offs2[nbase + tid] = make_int2(bs + ex, bs + ex + v);
  __syncthreads();
  for (int i = tid; i < tot; i += 256){
    unsigned pr = estage[i];
    int p = atomicAdd(&cu[pr >> 17], 1);
    col[p] = (int)(pr & 0x1FFFFu);
  }
}

// ---------------- MFMA GEMM 1 body: H(fp16)[n,64] = X(fp32)[n,128] @ W1, + logits --------
__device__ __forceinline__ void mg1_body(
    const float* __restrict__ X, const uint4* __restrict__ Wf,
    const float* __restrict__ a_src, const float* __restrict__ a_dst,
    uint2* __restrict__ H, float* __restrict__ as_, float* __restrict__ ad_, int n, int bb)
{
  int lane = threadIdx.x & 63, wv = threadIdx.x >> 6;
  int quad = lane >> 4, nn = lane & 15;
  int rowb = bb * 64 + wv * 16;
  int row = rowb + nn;
  bool ok = row < n;
  int rowc = ok ? row : n - 1;

  f16x8 af[4][4];
  #pragma unroll
  for (int t = 0; t < 4; ++t)
    #pragma unroll
    for (int s = 0; s < 4; ++s){
      FU fu; fu.u = Wf[(t * 4 + s) * 64 + lane];
      af[t][s] = fu.f;
    }

  const float4* Xr = (const float4*)(X + (size_t)rowc * 128);
  float4 xb[4][2];
  #pragma unroll
  for (int s = 0; s < 4; ++s){
    xb[s][0] = Xr[s * 8 + quad * 2];
    xb[s][1] = Xr[s * 8 + quad * 2 + 1];
  }

  f32x4 acc[4] = {};
  #pragma unroll
  for (int s = 0; s < 4; ++s){
    f16x8 bf;
    bf[0] = (_Float16)xb[s][0].x; bf[1] = (_Float16)xb[s][0].y;
    bf[2] = (_Float16)xb[s][0].z; bf[3] = (_Float16)xb[s][0].w;
    bf[4] = (_Float16)xb[s][1].x; bf[5] = (_Float16)xb[s][1].y;
    bf[6] = (_Float16)xb[s][1].z; bf[7] = (_Float16)xb[s][1].w;
    #pragma unroll
    for (int t = 0; t < 4; ++t)
      acc[t] = __builtin_amdgcn_mfma_f32_16x16x32_f16(af[t][s], bf, acc[t], 0, 0, 0);
  }

  if (ok){
    #pragma unroll
    for (int t = 0; t < 4; ++t){
      H2U p0, p1;
      p0.h = __floats2half2_rn(acc[t][0], acc[t][1]);
      p1.h = __floats2half2_rn(acc[t][2], acc[t][3]);
      H[(size_t)row * 16 + t * 4 + quad] = make_uint2(p0.u, p1.u);
    }
  }
  float sl = 0.f, dl = 0.f;
  #pragma unroll
  for (int t = 0; t < 4; ++t){
    float4 a4 = ((const float4*)a_src)[t * 4 + quad];
    float4 d4 = ((const float4*)a_dst)[t * 4 + quad];
    sl += acc[t][0] * a4.x + acc[t][1] * a4.y + acc[t][2] * a4.z + acc[t][3] * a4.w;
    dl += acc[t][0] * d4.x + acc[t][1] * d4.y + acc[t][2] * d4.z + acc[t][3] * d4.w;
  }
  sl += __shfl_xor(sl, 16, 64); sl += __shfl_xor(sl, 32, 64);
  dl += __shfl_xor(dl, 16, 64); dl += __shfl_xor(dl, 32, 64);
  if (lane < 16 && ok){ as_[row] = sl; ad_[row] = dl; }
}

// fused: blocks [0, B) run CSR finalize, blocks [B, ...) run GEMM1.
// Independent: p2 reads pairs (aliased to h2) + offsT, mgemm1 writes h1 — disjoint.
__global__ __launch_bounds__(256) void k_fused(
    const unsigned* __restrict__ pairs, const int* __restrict__ offsT,
    int NCH, int B, int N, int2* __restrict__ offs2, int* __restrict__ col,
    const float* __restrict__ X, const uint4* __restrict__ Wf,
    const float* __restrict__ a_src, const float* __restrict__ a_dst,
    uint2* __restrict__ H, float* __restrict__ as_, float* __restrict__ ad_)
{
  if ((int)blockIdx.x < B)
    p2_body(pairs, offsT, NCH, B, N, offs2, col, blockIdx.x);
  else
    mg1_body(X, Wf, a_src, a_dst, H, as_, ad_, N, blockIdx.x - B);
}

// ---------------- attention aggregation core (round-0 proven: 8 nodes/wave, x4 unroll) --
#define FMA8(e, hv) { const __half2* hp = (const __half2*)&(hv);               \
  a[0]=fmaf(e, __half2float(hp[0].x), a[0]); a[1]=fmaf(e, __half2float(hp[0].y), a[1]); \
  a[2]=fmaf(e, __half2float(hp[1].x), a[2]); a[3]=fmaf(e, __half2float(hp[1].y), a[3]); \
  a[4]=fmaf(e, __half2float(hp[2].x), a[4]); a[5]=fmaf(e, __half2float(hp[2].y), a[5]); \
  a[6]=fmaf(e, __half2float(hp[3].x), a[6]); a[7]=fmaf(e, __half2float(hp[3].y), a[7]); }

__device__ __forceinline__ void agg_core(
    const int2* __restrict__ offs2, const int* __restrict__ col,
    const uint4* __restrict__ H4, const float* __restrict__ as_, const float* __restrict__ ad_,
    int node, int c8, float& denom, float a[8])
{
  int2 be2 = offs2[node];
  int beg = be2.x, d = be2.y - be2.x;
  int maxd = d;
  maxd = max(maxd, __shfl_xor(maxd, 8, 64));
  maxd = max(maxd, __shfl_xor(maxd, 16, 64));
  maxd = max(maxd, __shfl_xor(maxd, 32, 64));
  float adv = ad_[node];
  float exs = __expf(lrelu(as_[node] + adv));
  uint4 hself = H4[(size_t)node * 8 + c8];
  denom = exs;
  { const __half2* hp = (const __half2*)&hself;
    #pragma unroll
    for (int i = 0; i < 4; ++i){
      a[2*i]   = exs * __half2float(hp[i].x);
      a[2*i+1] = exs * __half2float(hp[i].y);
    } }
  for (int j = 0; j < maxd; j += 4){
    int ss[4]; float asv[4]; uint4 hv[4];
    #pragma unroll
    for (int u = 0; u < 4; ++u) ss[u] = (j + u < d) ? col[beg + j + u] : 0;
    #pragma unroll
    for (int u = 0; u < 4; ++u) asv[u] = as_[ss[u]];
    #pragma unroll
    for (int u = 0; u < 4; ++u) hv[u] = H4[(size_t)ss[u] * 8 + c8];
    #pragma unroll
    for (int u = 0; u < 4; ++u){
      float e = (j + u < d) ? __expf(lrelu(asv[u] + adv)) : 0.f;
      denom += e;
      FMA8(e, hv[u])
    }
  }
}

// ---------------- fused agg1 + GEMM2: one block = 32 nodes ----------------
__global__ __launch_bounds__(256) void k_agg1f(
    const int2* __restrict__ offs2, const int* __restrict__ col,
    const uint4* __restrict__ H4, const float* __restrict__ as_, const float* __restrict__ ad_,
    const float* __restrict__ bias, const uint4* __restrict__ W2f,
    const float* __restrict__ a_src2, const float* __restrict__ a_dst2,
    uint2* __restrict__ H2out, float* __restrict__ as2_, float* __restrict__ ad2_, int n)
{
  // 72 halves/row (36 uints, 144 B stride): breaks the 128 B power-of-2 bank pattern
  __shared__ unsigned uhl[32][36];
  int lane = threadIdx.x & 63, w = threadIdx.x >> 6;
  int m = lane >> 3, c8 = lane & 7;
  int node0 = blockIdx.x * 32 + w * 8 + m;
  bool ok = node0 < n;
  int node = ok ? node0 : n - 1;
  float denom; float a[8];
  agg_core(offs2, col, H4, as_, ad_, node, c8, denom, a);
  float inv = 1.f / denom;
  float4 b0 = *(const float4*)&bias[8 * c8];
  float4 b1 = *(const float4*)&bias[8 * c8 + 4];
  float bb[8] = {b0.x, b0.y, b0.z, b0.w, b1.x, b1.y, b1.z, b1.w};
  int ln = w * 8 + m;
  #pragma unroll
  for (int i = 0; i < 4; ++i){
    float v0 = elu_fast(fmaf(a[2*i],   inv, bb[2*i]));
    float v1 = elu_fast(fmaf(a[2*i+1], inv, bb[2*i+1]));
    __half2 h = __floats2half2_rn(v0, v1);
    uhl[ln][c8 * 4 + i] = *(unsigned*)&h;
  }
  __syncthreads();

  // -------- phase 2: 32-row GEMM on waves 0-1 (rows w*16+nn) --------
  if (w < 2){
    int quad = lane >> 4, nn = lane & 15;
    int lrow = w * 16 + nn;
    int row = blockIdx.x * 32 + lrow;
    bool ok2 = row < n;

    f16x8 af[4][2];
    #pragma unroll
    for (int t = 0; t < 4; ++t)
      #pragma unroll
      for (int s = 0; s < 2; ++s){
        FU fu; fu.u = W2f[(t * 2 + s) * 64 + lane];
        af[t][s] = fu.f;
      }

    f16x8 bf[2];
    #pragma unroll
    for (int s = 0; s < 2; ++s){
      FU fu; fu.u = ((const uint4*)&uhl[lrow][0])[s * 4 + quad];
      bf[s] = fu.f;
    }

    f32x4 acc[4] = {};
    #pragma unroll
    for (int s = 0; s < 2; ++s)
      #pragma unroll
      for (int t = 0; t < 4; ++t)
        acc[t] = __builtin_amdgcn_mfma_f32_16x16x32_f16(af[t][s], bf[s], acc[t], 0, 0, 0);

    if (ok2){
      #pragma unroll
      for (int t = 0; t < 4; ++t){
        H2U p0, p1;
        p0.h = __floats2half2_rn(acc[t][0], acc[t][1]);
        p1.h = __floats2half2_rn(acc[t][2], acc[t][3]);
        H2out[(size_t)row * 16 + t * 4 + quad] = make_uint2(p0.u, p1.u);
      }
    }
    float sl = 0.f, dl = 0.f;
    #pragma unroll
    for (int t = 0; t < 4; ++t){
      float4 a4 = ((const float4*)a_src2)[t * 4 + quad];
      float4 d4 = ((const float4*)a_dst2)[t * 4 + quad];
      sl += acc[t][0] * a4.x + acc[t][1] * a4.y + acc[t][2] * a4.z + acc[t][3] * a4.w;
      dl += acc[t][0] * d4.x + acc[t][1] * d4.y + acc[t][2] * d4.z + acc[t][3] * d4.w;
    }
    sl += __shfl_xor(sl, 16, 64); sl += __shfl_xor(sl, 32, 64);
    dl += __shfl_xor(dl, 16, 64); dl += __shfl_xor(dl, 32, 64);
    if (lane < 16 && ok2){ as2_[row] = sl; ad2_[row] = dl; }
  }
}

// ---------------- agg2: layer-2 aggregation + output head (round-0 proven) ----------------
__global__ __launch_bounds__(256) void k_agg2(
    const int2* __restrict__ offs2, const int* __restrict__ col,
    const uint4* __restrict__ H4, const float* __restrict__ as_, const float* __restrict__ ad_,
    const float* __restrict__ bias, const float* __restrict__ Wout, const float* __restrict__ bout,
    float* __restrict__ out, int n)
{
  int lane = threadIdx.x & 63, w = threadIdx.x >> 6;
  int m = lane >> 3, c8 = lane & 7;
  int node0 = blockIdx.x * 32 + w * 8 + m;
  bool ok = node0 < n;
  int node = ok ? node0 : n - 1;
  float denom; float a[8];
  agg_core(offs2, col, H4, as_, ad_, node, c8, denom, a);
  float inv = 1.f / denom;
  float4 b0 = *(const float4*)&bias[8 * c8];
  float4 b1 = *(const float4*)&bias[8 * c8 + 4];
  float4 w0 = *(const float4*)&Wout[8 * c8];
  float4 w1 = *(const float4*)&Wout[8 * c8 + 4];
  float bb[8] = {b0.x, b0.y, b0.z, b0.w, b1.x, b1.y, b1.z, b1.w};
  float ww[8] = {w0.x, w0.y, w0.z, w0.w, w1.x, w1.y, w1.z, w1.w};
  float p = 0.f;
  #pragma unroll
  for (int i = 0; i < 8; ++i)
    p += elu_fast(fmaf(a[i], inv, bb[i])) * ww[i];
  p += __shfl_xor(p, 1, 64); p += __shfl_xor(p, 2, 64); p += __shfl_xor(p, 4, 64);
  if (c8 == 0 && ok) out[node] = p + bout[0];
}

// ---------------- launch ----------------
extern "C" void kernel_launch(void* const* d_in, const int* in_sizes, int n_in,
                              void* d_out, int out_size, void* d_ws, size_t ws_size,
                              hipStream_t stream)
{
  const float* x    = (const float*)d_in[0];
  const int*   ei   = (const int*)d_in[1];   // int32 [2, E] flat
  const float* W1   = (const float*)d_in[2];
  const float* as1w = (const float*)d_in[3];
  const float* ad1w = (const float*)d_in[4];
  const float* b1   = (const float*)d_in[5];
  const float* W2   = (const float*)d_in[6];
  const float* as2w = (const float*)d_in[7];
  const float* ad2w = (const float*)d_in[8];
  const float* b2   = (const float*)d_in[9];
  const float* Wout = (const float*)d_in[10];
  const float* bout = (const float*)d_in[11];
  float* out = (float*)d_out;

  const int N = in_sizes[0] / 128;
  const int E = in_sizes[1] / 2;
  const int* srcA = ei;
  const int* dstA = ei + E;
  const int B   = (N + BKT_NODES - 1) >> BKT_SHIFT;   // 391 buckets; src < 2^17 required
  const int NCH = (E + P1_CHUNK - 1) / P1_CHUNK;      // 391 chunks (must be <= 512 for p2 scan)

  char* p = (char*)d_ws;
  auto alloc = [&](size_t bytes){ char* r = p; p += (bytes + 255) & ~255ull; return r; };
  int2*  offs2  = (int2*)alloc((size_t)N * 8);
  int*   col    = (int*)alloc((size_t)B * BKT_FCAP * 4);       // padded CSR col (9.6 MB)
  int*   offsT  = (int*)alloc((size_t)NCH * (B + 1) * 4);      // per-chunk bucket offsets (613 KB)
  float* vas1 = (float*)alloc((size_t)N * 4);
  float* vad1 = (float*)alloc((size_t)N * 4);
  float* vas2 = (float*)alloc((size_t)N * 4);
  float* vad2 = (float*)alloc((size_t)N * 4);
  uint4* w1f  = (uint4*)alloc(16 * 64 * 16);
  uint4* w2f  = (uint4*)alloc(8 * 64 * 16);
  uint2* h1   = (uint2*)alloc((size_t)N * 64 * 2);   // fp16 [N,64] (layer-1 features)
  uint2* h2   = (uint2*)alloc((size_t)N * 64 * 2);   // fp16 [N,64] (layer-2 features)
  // pairs aliases h2 (NOT h1): p2 reads pairs while mgemm1 writes h1 concurrently;
  // h2 is first written by k_agg1f, after pairs is dead. (6.4 MB <= 12.8 MB)
  unsigned* pairs = (unsigned*)h2;

  k_p1<<<NCH, 512, 0, stream>>>(srcA, dstA, E, B, pairs, offsT, W1, W2, w1f, w2f);

  int gblocks = (N + 63) / 64;
  int ablocks = (N + 31) / 32;
  // p2 (CSR finalize) || mgemm1 (layer-1 GEMM) — independent, complementary pipes
  k_fused<<<B + gblocks, 256, 0, stream>>>(pairs, offsT, NCH, B, N, offs2, col,
                                           x, w1f, as1w, ad1w, h1, vas1, vad1);
  k_agg1f <<<ablocks, 256, 0, stream>>>(offs2, col, (const uint4*)h1, vas1, vad1, b1,
                                        w2f, as2w, ad2w, h2, vas2, vad2, N);
  k_agg2  <<<ablocks, 256, 0, stream>>>(offs2, col, (const uint4*)h2, vas2, vad2, b2, Wout, bout, out, N);
}

// Round 9
// 220.355 us; speedup vs baseline: 1.3356x; 1.0103x over previous
//
#include <hip/hip_runtime.h>
#include <hip/hip_fp16.h>
#include <math.h>

#define NEG_SLOPE 0.2f
#define BKT_SHIFT 8
#define BKT_NODES (1 << BKT_SHIFT)       // 256 nodes per bucket
#define BKT_FCAP 6144                    // fixed col capacity per bucket (avg 4092, 32-sigma)
#define P1_CHUNK 4096                    // edges per p1 block (block-owned region)
#define SEG_SHIFT 14                     // src segments of 16384 nodes (2.1 MB of H rows)

typedef _Float16 f16x8 __attribute__((ext_vector_type(8)));
typedef float    f32x4 __attribute__((ext_vector_type(4)));
union FU  { uint4 u; f16x8 f; };
union H2U { __half2 h; unsigned u; };

__device__ __forceinline__ float lrelu(float x){ return fmaxf(x, NEG_SLOPE * x); }
__device__ __forceinline__ float elu_fast(float x){
  float t = __expf(fminf(x, 0.f)) - 1.f;
  return x > 0.f ? x : t;
}

// ---------------- p1: block-owned counting sort of 4096 edges ----------------
// Block i owns pairs[i*4096 .. i*4096+cnt) grouped by bucket (b = dst>>8) and writes
// offsT[i*(B+1)+b] = exclusive start of bucket b's run (offsT[i*(B+1)+B] = cnt).
// No global atomics, no memset, fully coalesced writes. 512 threads for TLP.
// Block 0 additionally packs the W fragments.
__global__ __launch_bounds__(512) void k_p1(const int* __restrict__ src, const int* __restrict__ dst,
                                            int E, int B,
                                            unsigned* __restrict__ pairs, int* __restrict__ offsT,
                                            const float* __restrict__ W1, const float* __restrict__ W2,
                                            uint4* __restrict__ W1f, uint4* __restrict__ W2f){
  __shared__ int h[512], cur[512];
  __shared__ unsigned stage[P1_CHUNK];
  int tid = threadIdx.x;
  if (blockIdx.x == 0){
    // W1 fragments: fs = t*4+s (t,s in 0..3); W2: fs = t*2+s (t 0..3, s 0..1)
    for (int idx = tid; idx < 16 * 64; idx += 512){
      int lane = idx & 63, fs = idx >> 6;
      int t = fs >> 2, s = fs & 3;
      int m = lane & 15, quad = lane >> 4;
      f16x8 v;
      #pragma unroll
      for (int j = 0; j < 8; ++j)
        v[j] = (_Float16)W1[(s * 32 + quad * 8 + j) * 64 + t * 16 + m];
      FU fu; fu.f = v;
      W1f[fs * 64 + lane] = fu.u;
    }
    for (int idx = tid; idx < 8 * 64; idx += 512){
      int lane = idx & 63, fs = idx >> 6;
      int t = fs >> 1, s = fs & 1;
      int m = lane & 15, quad = lane >> 4;
      f16x8 v;
      #pragma unroll
      for (int j = 0; j < 8; ++j)
        v[j] = (_Float16)W2[(s * 32 + quad * 8 + j) * 64 + t * 16 + m];
      FU fu; fu.f = v;
      W2f[fs * 64 + lane] = fu.u;
    }
  }
  h[tid] = 0;
  __syncthreads();
  int beg = blockIdx.x * P1_CHUNK;
  int end = min(beg + P1_CHUNK, E);
  int cnt = end - beg;
  int m4 = cnt >> 2;
  const int4* d4 = (const int4*)(dst + beg);
  const int4* s4 = (const int4*)(src + beg);
  for (int i = tid; i < m4; i += 512){
    int4 d = d4[i];
    atomicAdd(&h[d.x >> BKT_SHIFT], 1); atomicAdd(&h[d.y >> BKT_SHIFT], 1);
    atomicAdd(&h[d.z >> BKT_SHIFT], 1); atomicAdd(&h[d.w >> BKT_SHIFT], 1);
  }
  for (int i = (m4 << 2) + tid; i < cnt; i += 512)
    atomicAdd(&h[dst[beg + i] >> BKT_SHIFT], 1);
  __syncthreads();
  // inclusive Hillis-Steele scan over h[0..512)
  int v = h[tid];
  for (int o = 1; o < 512; o <<= 1){
    int x = (tid >= o) ? h[tid - o] : 0;
    __syncthreads();
    h[tid] += x;
    __syncthreads();
  }
  int e = h[tid] - v;                    // exclusive prefix
  cur[tid] = e;
  int* orow = offsT + (size_t)blockIdx.x * (B + 1);
  if (tid <= B) orow[tid] = e;           // orow[B] = total cnt (buckets >= B empty)
  __syncthreads();
  // scatter into LDS stage, grouped by bucket
  for (int i = tid; i < m4; i += 512){
    int4 d = d4[i]; int4 s = s4[i];
    int p0 = atomicAdd(&cur[d.x >> BKT_SHIFT], 1);
    stage[p0] = ((unsigned)(d.x & (BKT_NODES-1)) << 17) | (unsigned)s.x;
    int p1 = atomicAdd(&cur[d.y >> BKT_SHIFT], 1);
    stage[p1] = ((unsigned)(d.y & (BKT_NODES-1)) << 17) | (unsigned)s.y;
    int p2 = atomicAdd(&cur[d.z >> BKT_SHIFT], 1);
    stage[p2] = ((unsigned)(d.z & (BKT_NODES-1)) << 17) | (unsigned)s.z;
    int p3 = atomicAdd(&cur[d.w >> BKT_SHIFT], 1);
    stage[p3] = ((unsigned)(d.w & (BKT_NODES-1)) << 17) | (unsigned)s.w;
  }
  for (int i = (m4 << 2) + tid; i < cnt; i += 512){
    int d = dst[beg + i], s = src[beg + i];
    int p = atomicAdd(&cur[d >> BKT_SHIFT], 1);
    stage[p] = ((unsigned)(d & (BKT_NODES-1)) << 17) | (unsigned)s;
  }
  __syncthreads();
  // coalesced writeout of the block's region
  unsigned* prow = pairs + (size_t)blockIdx.x * P1_CHUNK;
  for (int i = tid; i < cnt; i += 512) prow[i] = stage[i];
}

// ---------------- p2: per-bucket CSR finalize from block-owned runs ----------------
// Gathers bucket b's runs into LDS, then a 2048-bin (node x src-segment) counting sort
// places each node's edge list in src-segment-ascending order -> agg gathers concentrate
// in a ~2-4MB window that fits each XCD L2 (cuts the ~7x H-table re-fetch).
__device__ __forceinline__ void p2_body(const unsigned* __restrict__ pairs,
                                        const int* __restrict__ offsT,
                                        int NCH, int B, int N,
                                        int2* __restrict__ offs2, int* __restrict__ col, int b){
  __shared__ int rbase[512], scant[256];
  __shared__ int sc2[2048];
  __shared__ unsigned estage[BKT_FCAP];
  int tid = threadIdx.x;
  int nbase = b << BKT_SHIFT;
  int bs = b * BKT_FCAP;
  // run descriptors for chunks tid and tid+256
  int i0 = tid, i1 = tid + 256;
  int st0 = 0, ln0 = 0, st1 = 0, ln1 = 0;
  if (i0 < NCH){ int o = offsT[(size_t)i0 * (B + 1) + b]; st0 = o; ln0 = offsT[(size_t)i0 * (B + 1) + b + 1] - o; }
  if (i1 < NCH){ int o = offsT[(size_t)i1 * (B + 1) + b]; st1 = o; ln1 = offsT[(size_t)i1 * (B + 1) + b + 1] - o; }
  rbase[tid] = ln0; rbase[tid + 256] = ln1;
  #pragma unroll
  for (int k = 0; k < 8; ++k) sc2[tid * 8 + k] = 0;
  __syncthreads();
  // inclusive scan over rbase[0..512) with 256 threads (2 lanes each, lockstep)
  for (int o = 1; o < 512; o <<= 1){
    int x0 = (tid >= o) ? rbase[tid - o] : 0;
    int x1 = rbase[tid + 256 - o];       // tid+256 >= 256 >= o always
    __syncthreads();
    rbase[tid] += x0; rbase[tid + 256] += x1;
    __syncthreads();
  }
  int tot = rbase[511];
  int r0 = rbase[tid] - ln0, r1 = rbase[tid + 256] - ln1;
  // copy runs into estage (thread-serial, ~10.5 edges/run, L2-resident source)
  for (int j = 0; j < ln0; ++j) estage[r0 + j] = pairs[(size_t)i0 * P1_CHUNK + st0 + j];
  for (int j = 0; j < ln1; ++j) estage[r1 + j] = pairs[(size_t)i1 * P1_CHUNK + st1 + j];
  __syncthreads();
  // hist into (node*8 + src_segment) bins
  for (int i = tid; i < tot; i += 256){
    unsigned pr = estage[i];
    int key = (int)(pr >> 17) * 8 + (int)((pr & 0x1FFFFu) >> SEG_SHIFT);
    atomicAdd(&sc2[key], 1);
  }
  __syncthreads();
  // per-node (= per-thread) bin sums + 256-scan for node bases
  int loc[8]; int s = 0;
  #pragma unroll
  for (int k = 0; k < 8; ++k){ loc[k] = sc2[tid * 8 + k]; s += loc[k]; }
  scant[tid] = s;
  __syncthreads();
  for (int o = 1; o < 256; o <<= 1){
    int x = (tid >= o) ? scant[tid - o] : 0;
    __syncthreads();
    scant[tid] += x;
    __syncthreads();
  }
  int ex = scant[tid] - s;               // node-start exclusive prefix
  if (nbase + tid < N) offs2[nbase + tid] = make_int2(bs + ex, bs + ex + s);
  int run = bs + ex;
  #pragma unroll
  for (int k = 0; k < 8; ++k){ int c = loc[k]; sc2[tid * 8 + k] = run; run += c; }
  __syncthreads();
  // place in (node, segment) order
  for (int i = tid; i < tot; i += 256){
    unsigned pr = estage[i];
    int key = (int)(pr >> 17) * 8 + (int)((pr & 0x1FFFFu) >> SEG_SHIFT);
    int p = atomicAdd(&sc2[key], 1);
    col[p] = (int)(pr & 0x1FFFFu);
  }
}

// ---------------- MFMA GEMM 1 body: H(fp16)[n,64] = X(fp32)[n,128] @ W1, + logits --------
__device__ __forceinline__ void mg1_body(
    const float* __restrict__ X, const uint4* __restrict__ Wf,
    const float* __restrict__ a_src, const float* __restrict__ a_dst,
    uint2* __restrict__ H, float* __restrict__ as_, float* __restrict__ ad_, int n, int bb)
{
  int lane = threadIdx.x & 63, wv = threadIdx.x >> 6;
  int quad = lane >> 4, nn = lane & 15;
  int rowb = bb * 64 + wv * 16;
  int row = rowb + nn;
  bool ok = row < n;
  int rowc = ok ? row : n - 1;

  f16x8 af[4][4];
  #pragma unroll
  for (int t = 0; t < 4; ++t)
    #pragma unroll
    for (int s = 0; s < 4; ++s){
      FU fu; fu.u = Wf[(t * 4 + s) * 64 + lane];
      af[t][s] = fu.f;
    }

  const float4* Xr = (const float4*)(X + (size_t)rowc * 128);
  float4 xb[4][2];
  #pragma unroll
  for (int s = 0; s < 4; ++s){
    xb[s][0] = Xr[s * 8 + quad * 2];
    xb[s][1] = Xr[s * 8 + quad * 2 + 1];
  }

  f32x4 acc[4] = {};
  #pragma unroll
  for (int s = 0; s < 4; ++s){
    f16x8 bf;
    bf[0] = (_Float16)xb[s][0].x; bf[1] = (_Float16)xb[s][0].y;
    bf[2] = (_Float16)xb[s][0].z; bf[3] = (_Float16)xb[s][0].w;
    bf[4] = (_Float16)xb[s][1].x; bf[5] = (_Float16)xb[s][1].y;
    bf[6] = (_Float16)xb[s][1].z; bf[7] = (_Float16)xb[s][1].w;
    #pragma unroll
    for (int t = 0; t < 4; ++t)
      acc[t] = __builtin_amdgcn_mfma_f32_16x16x32_f16(af[t][s], bf, acc[t], 0, 0, 0);
  }

  if (ok){
    #pragma unroll
    for (int t = 0; t < 4; ++t){
      H2U p0, p1;
      p0.h = __floats2half2_rn(acc[t][0], acc[t][1]);
      p1.h = __floats2half2_rn(acc[t][2], acc[t][3]);
      H[(size_t)row * 16 + t * 4 + quad] = make_uint2(p0.u, p1.u);
    }
  }
  float sl = 0.f, dl = 0.f;
  #pragma unroll
  for (int t = 0; t < 4; ++t){
    float4 a4 = ((const float4*)a_src)[t * 4 + quad];
    float4 d4 = ((const float4*)a_dst)[t * 4 + quad];
    sl += acc[t][0] * a4.x + acc[t][1] * a4.y + acc[t][2] * a4.z + acc[t][3] * a4.w;
    dl += acc[t][0] * d4.x + acc[t][1] * d4.y + acc[t][2] * d4.z + acc[t][3] * d4.w;
  }
  sl += __shfl_xor(sl, 16, 64); sl += __shfl_xor(sl, 32, 64);
  dl += __shfl_xor(dl, 16, 64); dl += __shfl_xor(dl, 32, 64);
  if (lane < 16 && ok){ as_[row] = sl; ad_[row] = dl; }
}

// fused: blocks [0, B) run CSR finalize, blocks [B, ...) run GEMM1.
// Independent: p2 reads pairs (aliased to h2) + offsT, mgemm1 writes h1 — disjoint.
__global__ __launch_bounds__(256) void k_fused(
    const unsigned* __restrict__ pairs, const int* __restrict__ offsT,
    int NCH, int B, int N, int2* __restrict__ offs2, int* __restrict__ col,
    const float* __restrict__ X, const uint4* __restrict__ Wf,
    const float* __restrict__ a_src, const float* __restrict__ a_dst,
    uint2* __restrict__ H, float* __restrict__ as_, float* __restrict__ ad_)
{
  if ((int)blockIdx.x < B)
    p2_body(pairs, offsT, NCH, B, N, offs2, col, blockIdx.x);
  else
    mg1_body(X, Wf, a_src, a_dst, H, as_, ad_, N, blockIdx.x - B);
}

// ---------------- attention aggregation core (round-0 proven: 8 nodes/wave, x4 unroll) --
#define FMA8(e, hv) { const __half2* hp = (const __half2*)&(hv);               \
  a[0]=fmaf(e, __half2float(hp[0].x), a[0]); a[1]=fmaf(e, __half2float(hp[0].y), a[1]); \
  a[2]=fmaf(e, __half2float(hp[1].x), a[2]); a[3]=fmaf(e, __half2float(hp[1].y), a[3]); \
  a[4]=fmaf(e, __half2float(hp[2].x), a[4]); a[5]=fmaf(e, __half2float(hp[2].y), a[5]); \
  a[6]=fmaf(e, __half2float(hp[3].x), a[6]); a[7]=fmaf(e, __half2float(hp[3].y), a[7]); }

__device__ __forceinline__ void agg_core(
    const int2* __restrict__ offs2, const int* __restrict__ col,
    const uint4* __restrict__ H4, const float* __restrict__ as_, const float* __restrict__ ad_,
    int node, int c8, float& denom, float a[8])
{
  int2 be2 = offs2[node];
  int beg = be2.x, d = be2.y - be2.x;
  int maxd = d;
  maxd = max(maxd, __shfl_xor(maxd, 8, 64));
  maxd = max(maxd, __shfl_xor(maxd, 16, 64));
  maxd = max(maxd, __shfl_xor(maxd, 32, 64));
  float adv = ad_[node];
  float exs = __expf(lrelu(as_[node] + adv));
  uint4 hself = H4[(size_t)node * 8 + c8];
  denom = exs;
  { const __half2* hp = (const __half2*)&hself;
    #pragma unroll
    for (int i = 0; i < 4; ++i){
      a[2*i]   = exs * __half2float(hp[i].x);
      a[2*i+1] = exs * __half2float(hp[i].y);
    } }
  for (int j = 0; j < maxd; j += 4){
    int ss[4]; float asv[4]; uint4 hv[4];
    #pragma unroll
    for (int u = 0; u < 4; ++u) ss[u] = (j + u < d) ? col[beg + j + u] : 0;
    #pragma unroll
    for (int u = 0; u < 4; ++u) asv[u] = as_[ss[u]];
    #pragma unroll
    for (int u = 0; u < 4; ++u) hv[u] = H4[(size_t)ss[u] * 8 + c8];
    #pragma unroll
    for (int u = 0; u < 4; ++u){
      float e = (j + u < d) ? __expf(lrelu(asv[u] + adv)) : 0.f;
      denom += e;
      FMA8(e, hv[u])
    }
  }
}

// ---------------- fused agg1 + GEMM2: one block = 32 nodes ----------------
__global__ __launch_bounds__(256) void k_agg1f(
    const int2* __restrict__ offs2, const int* __restrict__ col,
    const uint4* __restrict__ H4, const float* __restrict__ as_, const float* __restrict__ ad_,
    const float* __restrict__ bias, const uint4* __restrict__ W2f,
    const float* __restrict__ a_src2, const float* __restrict__ a_dst2,
    uint2* __restrict__ H2out, float* __restrict__ as2_, float* __restrict__ ad2_, int n)
{
  // 72 halves/row (36 uints, 144 B stride): breaks the 128 B power-of-2 bank pattern
  __shared__ unsigned uhl[32][36];
  int lane = threadIdx.x & 63, w = threadIdx.x >> 6;
  int m = lane >> 3, c8 = lane & 7;
  int node0 = blockIdx.x * 32 + w * 8 + m;
  bool ok = node0 < n;
  int node = ok ? node0 : n - 1;
  float denom; float a[8];
  agg_core(offs2, col, H4, as_, ad_, node, c8, denom, a);
  float inv = 1.f / denom;
  float4 b0 = *(const float4*)&bias[8 * c8];
  float4 b1 = *(const float4*)&bias[8 * c8 + 4];
  float bb[8] = {b0.x, b0.y, b0.z, b0.w, b1.x, b1.y, b1.z, b1.w};
  int ln = w * 8 + m;
  #pragma unroll
  for (int i = 0; i < 4; ++i){
    float v0 = elu_fast(fmaf(a[2*i],   inv, bb[2*i]));
    float v1 = elu_fast(fmaf(a[2*i+1], inv, bb[2*i+1]));
    __half2 h = __floats2half2_rn(v0, v1);
    uhl[ln][c8 * 4 + i] = *(unsigned*)&h;
  }
  __syncthreads();

  // -------- phase 2: 32-row GEMM on waves 0-1 (rows w*16+nn) --------
  if (w < 2){
    int quad = lane >> 4, nn = lane & 15;
    int lrow = w * 16 + nn;
    int row = blockIdx.x * 32 + lrow;
    bool ok2 = row < n;

    f16x8 af[4][2];
    #pragma unroll
    for (int t = 0; t < 4; ++t)
      #pragma unroll
      for (int s = 0; s < 2; ++s){
        FU fu; fu.u = W2f[(t * 2 + s) * 64 + lane];
        af[t][s] = fu.f;
      }

    f16x8 bf[2];
    #pragma unroll
    for (int s = 0; s < 2; ++s){
      FU fu; fu.u = ((const uint4*)&uhl[lrow][0])[s * 4 + quad];
      bf[s] = fu.f;
    }

    f32x4 acc[4] = {};
    #pragma unroll
    for (int s = 0; s < 2; ++s)
      #pragma unroll
      for (int t = 0; t < 4; ++t)
        acc[t] = __builtin_amdgcn_mfma_f32_16x16x32_f16(af[t][s], bf[s], acc[t], 0, 0, 0);

    if (ok2){
      #pragma unroll
      for (int t = 0; t < 4; ++t){
        H2U p0, p1;
        p0.h = __floats2half2_rn(acc[t][0], acc[t][1]);
        p1.h = __floats2half2_rn(acc[t][2], acc[t][3]);
        H2out[(size_t)row * 16 + t * 4 + quad] = make_uint2(p0.u, p1.u);
      }
    }
    float sl = 0.f, dl = 0.f;
    #pragma unroll
    for (int t = 0; t < 4; ++t){
      float4 a4 = ((const float4*)a_src2)[t * 4 + quad];
      float4 d4 = ((const float4*)a_dst2)[t * 4 + quad];
      sl += acc[t][0] * a4.x + acc[t][1] * a4.y + acc[t][2] * a4.z + acc[t][3] * a4.w;
      dl += acc[t][0] * d4.x + acc[t][1] * d4.y + acc[t][2] * d4.z + acc[t][3] * d4.w;
    }
    sl += __shfl_xor(sl, 16, 64); sl += __shfl_xor(sl, 32, 64);
    dl += __shfl_xor(dl, 16, 64); dl += __shfl_xor(dl, 32, 64);
    if (lane < 16 && ok2){ as2_[row] = sl; ad2_[row] = dl; }
  }
}

// ---------------- agg2: layer-2 aggregation + output head (round-0 proven) ----------------
__global__ __launch_bounds__(256) void k_agg2(
    const int2* __restrict__ offs2, const int* __restrict__ col,
    const uint4* __restrict__ H4, const float* __restrict__ as_, const float* __restrict__ ad_,
    const float* __restrict__ bias, const float* __restrict__ Wout, const float* __restrict__ bout,
    float* __restrict__ out, int n)
{
  int lane = threadIdx.x & 63, w = threadIdx.x >> 6;
  int m = lane >> 3, c8 = lane & 7;
  int node0 = blockIdx.x * 32 + w * 8 + m;
  bool ok = node0 < n;
  int node = ok ? node0 : n - 1;
  float denom; float a[8];
  agg_core(offs2, col, H4, as_, ad_, node, c8, denom, a);
  float inv = 1.f / denom;
  float4 b0 = *(const float4*)&bias[8 * c8];
  float4 b1 = *(const float4*)&bias[8 * c8 + 4];
  float4 w0 = *(const float4*)&Wout[8 * c8];
  float4 w1 = *(const float4*)&Wout[8 * c8 + 4];
  float bb[8] = {b0.x, b0.y, b0.z, b0.w, b1.x, b1.y, b1.z, b1.w};
  float ww[8] = {w0.x, w0.y, w0.z, w0.w, w1.x, w1.y, w1.z, w1.w};
  float p = 0.f;
  #pragma unroll
  for (int i = 0; i < 8; ++i)
    p += elu_fast(fmaf(a[i], inv, bb[i])) * ww[i];
  p += __shfl_xor(p, 1, 64); p += __shfl_xor(p, 2, 64); p += __shfl_xor(p, 4, 64);
  if (c8 == 0 && ok) out[node] = p + bout[0];
}

// ---------------- launch ----------------
extern "C" void kernel_launch(void* const* d_in, const int* in_sizes, int n_in,
                              void* d_out, int out_size, void* d_ws, size_t ws_size,
                              hipStream_t stream)
{
  const float* x    = (const float*)d_in[0];
  const int*   ei   = (const int*)d_in[1];   // int32 [2, E] flat
  const float* W1   = (const float*)d_in[2];
  const float* as1w = (const float*)d_in[3];
  const float* ad1w = (const float*)d_in[4];
  const float* b1   = (const float*)d_in[5];
  const float* W2   = (const float*)d_in[6];
  const float* as2w = (const float*)d_in[7];
  const float* ad2w = (const float*)d_in[8];
  const float* b2   = (const float*)d_in[9];
  const float* Wout = (const float*)d_in[10];
  const float* bout = (const float*)d_in[11];
  float* out = (float*)d_out;

  const int N = in_sizes[0] / 128;
  const int E = in_sizes[1] / 2;
  const int* srcA = ei;
  const int* dstA = ei + E;
  const int B   = (N + BKT_NODES - 1) >> BKT_SHIFT;   // 391 buckets; src < 2^17 required
  const int NCH = (E + P1_CHUNK - 1) / P1_CHUNK;      // 391 chunks (must be <= 512 for p2 scan)

  char* p = (char*)d_ws;
  auto alloc = [&](size_t bytes){ char* r = p; p += (bytes + 255) & ~255ull; return r; };
  int2*  offs2  = (int2*)alloc((size_t)N * 8);
  int*   col    = (int*)alloc((size_t)B * BKT_FCAP * 4);       // padded CSR col (9.6 MB)
  int*   offsT  = (int*)alloc((size_t)NCH * (B + 1) * 4);      // per-chunk bucket offsets (613 KB)
  float* vas1 = (float*)alloc((size_t)N * 4);
  float* vad1 = (float*)alloc((size_t)N * 4);
  float* vas2 = (float*)alloc((size_t)N * 4);
  float* vad2 = (float*)alloc((size_t)N * 4);
  uint4* w1f  = (uint4*)alloc(16 * 64 * 16);
  uint4* w2f  = (uint4*)alloc(8 * 64 * 16);
  uint2* h1   = (uint2*)alloc((size_t)N * 64 * 2);   // fp16 [N,64] (layer-1 features)
  uint2* h2   = (uint2*)alloc((size_t)N * 64 * 2);   // fp16 [N,64] (layer-2 features)
  // pairs aliases h2 (NOT h1): p2 reads pairs while mgemm1 writes h1 concurrently;
  // h2 is first written by k_agg1f, after pairs is dead. (6.4 MB <= 12.8 MB)
  unsigned* pairs = (unsigned*)h2;

  k_p1<<<NCH, 512, 0, stream>>>(srcA, dstA, E, B, pairs, offsT, W1, W2, w1f, w2f);

  int gblocks = (N + 63) / 64;
  int ablocks = (N + 31) / 32;
  // p2 (CSR finalize) || mgemm1 (layer-1 GEMM) — independent, complementary pipes
  k_fused<<<B + gblocks, 256, 0, stream>>>(pairs, offsT, NCH, B, N, offs2, col,
                                           x, w1f, as1w, ad1w, h1, vas1, vad1);
  k_agg1f <<<ablocks, 256, 0, stream>>>(offs2, col, (const uint4*)h1, vas1, vad1, b1,
                                        w2f, as2w, ad2w, h2, vas2, vad2, N);
  k_agg2  <<<ablocks, 256, 0, stream>>>(offs2, col, (const uint4*)h2, vas2, vad2, b2, Wout, bout, out, N);
}

// Round 10
// 216.953 us; speedup vs baseline: 1.3565x; 1.0157x over previous
//
#include <hip/hip_runtime.h>
#include <hip/hip_fp16.h>
#include <math.h>

#define NEG_SLOPE 0.2f
#define BKT_SHIFT 8
#define BKT_NODES (1 << BKT_SHIFT)       // 256 nodes per bucket
#define BKT_FCAP 6144                    // fixed col capacity per bucket (avg 4092, 32-sigma)
#define P1_CHUNK 4096                    // edges per p1 block (block-owned region)
#define SEG_SHIFT 14                     // src segments of 16384 nodes

typedef _Float16 f16x8 __attribute__((ext_vector_type(8)));
typedef float    f32x4 __attribute__((ext_vector_type(4)));
union FU  { uint4 u; f16x8 f; };
union H2U { __half2 h; unsigned u; };

__device__ __forceinline__ float lrelu(float x){ return fmaxf(x, NEG_SLOPE * x); }
__device__ __forceinline__ float elu_fast(float x){
  float t = __expf(fminf(x, 0.f)) - 1.f;
  return x > 0.f ? x : t;
}

// ---------------- p1: block-owned counting sort of 4096 edges ----------------
__global__ __launch_bounds__(512) void k_p1(const int* __restrict__ src, const int* __restrict__ dst,
                                            int E, int B,
                                            unsigned* __restrict__ pairs, int* __restrict__ offsT,
                                            const float* __restrict__ W1, const float* __restrict__ W2,
                                            uint4* __restrict__ W1f, uint4* __restrict__ W2f){
  __shared__ int h[512], cur[512];
  __shared__ unsigned stage[P1_CHUNK];
  int tid = threadIdx.x;
  if (blockIdx.x == 0){
    for (int idx = tid; idx < 16 * 64; idx += 512){
      int lane = idx & 63, fs = idx >> 6;
      int t = fs >> 2, s = fs & 3;
      int m = lane & 15, quad = lane >> 4;
      f16x8 v;
      #pragma unroll
      for (int j = 0; j < 8; ++j)
        v[j] = (_Float16)W1[(s * 32 + quad * 8 + j) * 64 + t * 16 + m];
      FU fu; fu.f = v;
      W1f[fs * 64 + lane] = fu.u;
    }
    for (int idx = tid; idx < 8 * 64; idx += 512){
      int lane = idx & 63, fs = idx >> 6;
      int t = fs >> 1, s = fs & 1;
      int m = lane & 15, quad = lane >> 4;
      f16x8 v;
      #pragma unroll
      for (int j = 0; j < 8; ++j)
        v[j] = (_Float16)W2[(s * 32 + quad * 8 + j) * 64 + t * 16 + m];
      FU fu; fu.f = v;
      W2f[fs * 64 + lane] = fu.u;
    }
  }
  h[tid] = 0;
  __syncthreads();
  int beg = blockIdx.x * P1_CHUNK;
  int end = min(beg + P1_CHUNK, E);
  int cnt = end - beg;
  int m4 = cnt >> 2;
  const int4* d4 = (const int4*)(dst + beg);
  const int4* s4 = (const int4*)(src + beg);
  for (int i = tid; i < m4; i += 512){
    int4 d = d4[i];
    atomicAdd(&h[d.x >> BKT_SHIFT], 1); atomicAdd(&h[d.y >> BKT_SHIFT], 1);
    atomicAdd(&h[d.z >> BKT_SHIFT], 1); atomicAdd(&h[d.w >> BKT_SHIFT], 1);
  }
  for (int i = (m4 << 2) + tid; i < cnt; i += 512)
    atomicAdd(&h[dst[beg + i] >> BKT_SHIFT], 1);
  __syncthreads();
  int v = h[tid];
  for (int o = 1; o < 512; o <<= 1){
    int x = (tid >= o) ? h[tid - o] : 0;
    __syncthreads();
    h[tid] += x;
    __syncthreads();
  }
  int e = h[tid] - v;
  cur[tid] = e;
  int* orow = offsT + (size_t)blockIdx.x * (B + 1);
  if (tid <= B) orow[tid] = e;
  __syncthreads();
  for (int i = tid; i < m4; i += 512){
    int4 d = d4[i]; int4 s = s4[i];
    int p0 = atomicAdd(&cur[d.x >> BKT_SHIFT], 1);
    stage[p0] = ((unsigned)(d.x & (BKT_NODES-1)) << 17) | (unsigned)s.x;
    int p1 = atomicAdd(&cur[d.y >> BKT_SHIFT], 1);
    stage[p1] = ((unsigned)(d.y & (BKT_NODES-1)) << 17) | (unsigned)s.y;
    int p2 = atomicAdd(&cur[d.z >> BKT_SHIFT], 1);
    stage[p2] = ((unsigned)(d.z & (BKT_NODES-1)) << 17) | (unsigned)s.z;
    int p3 = atomicAdd(&cur[d.w >> BKT_SHIFT], 1);
    stage[p3] = ((unsigned)(d.w & (BKT_NODES-1)) << 17) | (unsigned)s.w;
  }
  for (int i = (m4 << 2) + tid; i < cnt; i += 512){
    int d = dst[beg + i], s = src[beg + i];
    int p = atomicAdd(&cur[d >> BKT_SHIFT], 1);
    stage[p] = ((unsigned)(d & (BKT_NODES-1)) << 17) | (unsigned)s;
  }
  __syncthreads();
  unsigned* prow = pairs + (size_t)blockIdx.x * P1_CHUNK;
  for (int i = tid; i < cnt; i += 512) prow[i] = stage[i];
}

// ---------------- p2: per-bucket CSR finalize (2048-bin node x segment sort) ----------------
__device__ __forceinline__ void p2_body(const unsigned* __restrict__ pairs,
                                        const int* __restrict__ offsT,
                                        int NCH, int B, int N,
                                        int2* __restrict__ offs2, int* __restrict__ col, int b){
  __shared__ int rbase[512], scant[256];
  __shared__ int sc2[2048];
  __shared__ unsigned estage[BKT_FCAP];
  int tid = threadIdx.x;
  int nbase = b << BKT_SHIFT;
  int bs = b * BKT_FCAP;
  int i0 = tid, i1 = tid + 256;
  int st0 = 0, ln0 = 0, st1 = 0, ln1 = 0;
  if (i0 < NCH){ int o = offsT[(size_t)i0 * (B + 1) + b]; st0 = o; ln0 = offsT[(size_t)i0 * (B + 1) + b + 1] - o; }
  if (i1 < NCH){ int o = offsT[(size_t)i1 * (B + 1) + b]; st1 = o; ln1 = offsT[(size_t)i1 * (B + 1) + b + 1] - o; }
  rbase[tid] = ln0; rbase[tid + 256] = ln1;
  #pragma unroll
  for (int k = 0; k < 8; ++k) sc2[tid * 8 + k] = 0;
  __syncthreads();
  for (int o = 1; o < 512; o <<= 1){
    int x0 = (tid >= o) ? rbase[tid - o] : 0;
    int x1 = rbase[tid + 256 - o];
    __syncthreads();
    rbase[tid] += x0; rbase[tid + 256] += x1;
    __syncthreads();
  }
  int tot = rbase[511];
  int r0 = rbase[tid] - ln0, r1 = rbase[tid + 256] - ln1;
  for (int j = 0; j < ln0; ++j) estage[r0 + j] = pairs[(size_t)i0 * P1_CHUNK + st0 + j];
  for (int j = 0; j < ln1; ++j) estage[r1 + j] = pairs[(size_t)i1 * P1_CHUNK + st1 + j];
  __syncthreads();
  for (int i = tid; i < tot; i += 256){
    unsigned pr = estage[i];
    int key = (int)(pr >> 17) * 8 + (int)((pr & 0x1FFFFu) >> SEG_SHIFT);
    atomicAdd(&sc2[key], 1);
  }
  __syncthreads();
  int loc[8]; int s = 0;
  #pragma unroll
  for (int k = 0; k < 8; ++k){ loc[k] = sc2[tid * 8 + k]; s += loc[k]; }
  scant[tid] = s;
  __syncthreads();
  for (int o = 1; o < 256; o <<= 1){
    int x = (tid >= o) ? scant[tid - o] : 0;
    __syncthreads();
    scant[tid] += x;
    __syncthreads();
  }
  int ex = scant[tid] - s;
  if (nbase + tid < N) offs2[nbase + tid] = make_int2(bs + ex, bs + ex + s);
  int run = bs + ex;
  #pragma unroll
  for (int k = 0; k < 8; ++k){ int c = loc[k]; sc2[tid * 8 + k] = run; run += c; }
  __syncthreads();
  for (int i = tid; i < tot; i += 256){
    unsigned pr = estage[i];
    int key = (int)(pr >> 17) * 8 + (int)((pr & 0x1FFFFu) >> SEG_SHIFT);
    int p = atomicAdd(&sc2[key], 1);
    col[p] = (int)(pr & 0x1FFFFu);
  }
}

// ---------------- MFMA GEMM 1 body ----------------
__device__ __forceinline__ void mg1_body(
    const float* __restrict__ X, const uint4* __restrict__ Wf,
    const float* __restrict__ a_src, const float* __restrict__ a_dst,
    uint2* __restrict__ H, float* __restrict__ as_, float* __restrict__ ad_, int n, int bb)
{
  int lane = threadIdx.x & 63, wv = threadIdx.x >> 6;
  int quad = lane >> 4, nn = lane & 15;
  int rowb = bb * 64 + wv * 16;
  int row = rowb + nn;
  bool ok = row < n;
  int rowc = ok ? row : n - 1;

  f16x8 af[4][4];
  #pragma unroll
  for (int t = 0; t < 4; ++t)
    #pragma unroll
    for (int s = 0; s < 4; ++s){
      FU fu; fu.u = Wf[(t * 4 + s) * 64 + lane];
      af[t][s] = fu.f;
    }

  const float4* Xr = (const float4*)(X + (size_t)rowc * 128);
  float4 xb[4][2];
  #pragma unroll
  for (int s = 0; s < 4; ++s){
    xb[s][0] = Xr[s * 8 + quad * 2];
    xb[s][1] = Xr[s * 8 + quad * 2 + 1];
  }

  f32x4 acc[4] = {};
  #pragma unroll
  for (int s = 0; s < 4; ++s){
    f16x8 bf;
    bf[0] = (_Float16)xb[s][0].x; bf[1] = (_Float16)xb[s][0].y;
    bf[2] = (_Float16)xb[s][0].z; bf[3] = (_Float16)xb[s][0].w;
    bf[4] = (_Float16)xb[s][1].x; bf[5] = (_Float16)xb[s][1].y;
    bf[6] = (_Float16)xb[s][1].z; bf[7] = (_Float16)xb[s][1].w;
    #pragma unroll
    for (int t = 0; t < 4; ++t)
      acc[t] = __builtin_amdgcn_mfma_f32_16x16x32_f16(af[t][s], bf, acc[t], 0, 0, 0);
  }

  if (ok){
    #pragma unroll
    for (int t = 0; t < 4; ++t){
      H2U p0, p1;
      p0.h = __floats2half2_rn(acc[t][0], acc[t][1]);
      p1.h = __floats2half2_rn(acc[t][2], acc[t][3]);
      H[(size_t)row * 16 + t * 4 + quad] = make_uint2(p0.u, p1.u);
    }
  }
  float sl = 0.f, dl = 0.f;
  #pragma unroll
  for (int t = 0; t < 4; ++t){
    float4 a4 = ((const float4*)a_src)[t * 4 + quad];
    float4 d4 = ((const float4*)a_dst)[t * 4 + quad];
    sl += acc[t][0] * a4.x + acc[t][1] * a4.y + acc[t][2] * a4.z + acc[t][3] * a4.w;
    dl += acc[t][0] * d4.x + acc[t][1] * d4.y + acc[t][2] * d4.z + acc[t][3] * d4.w;
  }
  sl += __shfl_xor(sl, 16, 64); sl += __shfl_xor(sl, 32, 64);
  dl += __shfl_xor(dl, 16, 64); dl += __shfl_xor(dl, 32, 64);
  if (lane < 16 && ok){ as_[row] = sl; ad_[row] = dl; }
}

__global__ __launch_bounds__(256) void k_fused(
    const unsigned* __restrict__ pairs, const int* __restrict__ offsT,
    int NCH, int B, int N, int2* __restrict__ offs2, int* __restrict__ col,
    const float* __restrict__ X, const uint4* __restrict__ Wf,
    const float* __restrict__ a_src, const float* __restrict__ a_dst,
    uint2* __restrict__ H, float* __restrict__ as_, float* __restrict__ ad_)
{
  if ((int)blockIdx.x < B)
    p2_body(pairs, offsT, NCH, B, N, offs2, col, blockIdx.x);
  else
    mg1_body(X, Wf, a_src, a_dst, H, as_, ad_, N, blockIdx.x - B);
}

// ---------------- attention aggregation core (round-0 proven) ----------------
#define FMA8(e, hv) { const __half2* hp = (const __half2*)&(hv);               \
  a[0]=fmaf(e, __half2float(hp[0].x), a[0]); a[1]=fmaf(e, __half2float(hp[0].y), a[1]); \
  a[2]=fmaf(e, __half2float(hp[1].x), a[2]); a[3]=fmaf(e, __half2float(hp[1].y), a[3]); \
  a[4]=fmaf(e, __half2float(hp[2].x), a[4]); a[5]=fmaf(e, __half2float(hp[2].y), a[5]); \
  a[6]=fmaf(e, __half2float(hp[3].x), a[6]); a[7]=fmaf(e, __half2float(hp[3].y), a[7]); }

__device__ __forceinline__ void agg_core(
    const int2* __restrict__ offs2, const int* __restrict__ col,
    const uint4* __restrict__ H4, const float* __restrict__ as_, const float* __restrict__ ad_,
    int node, int c8, float& denom, float a[8])
{
  int2 be2 = offs2[node];
  int beg = be2.x, d = be2.y - be2.x;
  int maxd = d;
  maxd = max(maxd, __shfl_xor(maxd, 8, 64));
  maxd = max(maxd, __shfl_xor(maxd, 16, 64));
  maxd = max(maxd, __shfl_xor(maxd, 32, 64));
  float adv = ad_[node];
  float exs = __expf(lrelu(as_[node] + adv));
  uint4 hself = H4[(size_t)node * 8 + c8];
  denom = exs;
  { const __half2* hp = (const __half2*)&hself;
    #pragma unroll
    for (int i = 0; i < 4; ++i){
      a[2*i]   = exs * __half2float(hp[i].x);
      a[2*i+1] = exs * __half2float(hp[i].y);
    } }
  for (int j = 0; j < maxd; j += 4){
    int ss[4]; float asv[4]; uint4 hv[4];
    #pragma unroll
    for (int u = 0; u < 4; ++u) ss[u] = (j + u < d) ? col[beg + j + u] : 0;
    #pragma unroll
    for (int u = 0; u < 4; ++u) asv[u] = as_[ss[u]];
    #pragma unroll
    for (int u = 0; u < 4; ++u) hv[u] = H4[(size_t)ss[u] * 8 + c8];
    #pragma unroll
    for (int u = 0; u < 4; ++u){
      float e = (j + u < d) ? __expf(lrelu(asv[u] + adv)) : 0.f;
      denom += e;
      FMA8(e, hv[u])
    }
  }
}

// block-local degree-balanced node assignment: rank-sort the block's 32 nodes by degree
// so each wave's 8 nodes have similar degree -> wave-max trips drop ~15% with ZERO
// locality change (same 32-node window, outputs scatter within the same lines).
#define DEGSORT32(offs2, base, n, dg, prm)                                     \
  { int tid_ = threadIdx.x;                                                    \
    if (tid_ < 32){                                                            \
      int nd_ = min(base + tid_, n - 1);                                       \
      int2 be_ = offs2[nd_];                                                   \
      dg[tid_] = be_.y - be_.x;                                                \
    }                                                                          \
    __syncthreads();                                                           \
    if (tid_ < 32){                                                            \
      int d_ = dg[tid_]; int r_ = 0;                                           \
      _Pragma("unroll")                                                        \
      for (int j_ = 0; j_ < 32; ++j_){                                         \
        int dj_ = dg[j_];                                                      \
        r_ += (dj_ < d_) || (dj_ == d_ && j_ < tid_);                          \
      }                                                                        \
      prm[r_] = tid_;                                                          \
    }                                                                          \
    __syncthreads(); }

// ---------------- fused agg1 + GEMM2: one block = 32 nodes ----------------
__global__ __launch_bounds__(256) void k_agg1f(
    const int2* __restrict__ offs2, const int* __restrict__ col,
    const uint4* __restrict__ H4, const float* __restrict__ as_, const float* __restrict__ ad_,
    const float* __restrict__ bias, const uint4* __restrict__ W2f,
    const float* __restrict__ a_src2, const float* __restrict__ a_dst2,
    uint2* __restrict__ H2out, float* __restrict__ as2_, float* __restrict__ ad2_, int n)
{
  // 72 halves/row (36 uints, 144 B stride): breaks the 128 B power-of-2 bank pattern
  __shared__ unsigned uhl[32][36];
  __shared__ int dg[32], prm[32];
  int lane = threadIdx.x & 63, w = threadIdx.x >> 6;
  int m = lane >> 3, c8 = lane & 7;
  int base = blockIdx.x * 32;
  DEGSORT32(offs2, base, n, dg, prm)
  int sl = prm[w * 8 + m];          // local node index (degree-balanced assignment)
  int node0 = base + sl;
  bool ok = node0 < n;
  int node = ok ? node0 : n - 1;
  float denom; float a[8];
  agg_core(offs2, col, H4, as_, ad_, node, c8, denom, a);
  float inv = 1.f / denom;
  float4 b0 = *(const float4*)&bias[8 * c8];
  float4 b1 = *(const float4*)&bias[8 * c8 + 4];
  float bb[8] = {b0.x, b0.y, b0.z, b0.w, b1.x, b1.y, b1.z, b1.w};
  // uhl is indexed by LOCAL NODE index sl (perm is a bijection -> every row written once)
  #pragma unroll
  for (int i = 0; i < 4; ++i){
    float v0 = elu_fast(fmaf(a[2*i],   inv, bb[2*i]));
    float v1 = elu_fast(fmaf(a[2*i+1], inv, bb[2*i+1]));
    __half2 h = __floats2half2_rn(v0, v1);
    uhl[sl][c8 * 4 + i] = *(unsigned*)&h;
  }
  __syncthreads();

  // -------- phase 2: 32-row GEMM on waves 0-1 (rows w*16+nn, positional) --------
  if (w < 2){
    int quad = lane >> 4, nn = lane & 15;
    int lrow = w * 16 + nn;
    int row = base + lrow;
    bool ok2 = row < n;

    f16x8 af[4][2];
    #pragma unroll
    for (int t = 0; t < 4; ++t)
      #pragma unroll
      for (int s = 0; s < 2; ++s){
        FU fu; fu.u = W2f[(t * 2 + s) * 64 + lane];
        af[t][s] = fu.f;
      }

    f16x8 bf[2];
    #pragma unroll
    for (int s = 0; s < 2; ++s){
      FU fu; fu.u = ((const uint4*)&uhl[lrow][0])[s * 4 + quad];
      bf[s] = fu.f;
    }

    f32x4 acc[4] = {};
    #pragma unroll
    for (int s = 0; s < 2; ++s)
      #pragma unroll
      for (int t = 0; t < 4; ++t)
        acc[t] = __builtin_amdgcn_mfma_f32_16x16x32_f16(af[t][s], bf[s], acc[t], 0, 0, 0);

    if (ok2){
      #pragma unroll
      for (int t = 0; t < 4; ++t){
        H2U p0, p1;
        p0.h = __floats2half2_rn(acc[t][0], acc[t][1]);
        p1.h = __floats2half2_rn(acc[t][2], acc[t][3]);
        H2out[(size_t)row * 16 + t * 4 + quad] = make_uint2(p0.u, p1.u);
      }
    }
    float sl2 = 0.f, dl2 = 0.f;
    #pragma unroll
    for (int t = 0; t < 4; ++t){
      float4 a4 = ((const float4*)a_src2)[t * 4 + quad];
      float4 d4 = ((const float4*)a_dst2)[t * 4 + quad];
      sl2 += acc[t][0] * a4.x + acc[t][1] * a4.y + acc[t][2] * a4.z + acc[t][3] * a4.w;
      dl2 += acc[t][0] * d4.x + acc[t][1] * d4.y + acc[t][2] * d4.z + acc[t][3] * d4.w;
    }
    sl2 += __shfl_xor(sl2, 16, 64); sl2 += __shfl_xor(sl2, 32, 64);
    dl2 += __shfl_xor(dl2, 16, 64); dl2 += __shfl_xor(dl2, 32, 64);
    if (lane < 16 && ok2){ as2_[row] = sl2; ad2_[row] = dl2; }
  }
}

// ---------------- agg2: layer-2 aggregation + output head ----------------
__global__ __launch_bounds__(256) void k_agg2(
    const int2* __restrict__ offs2, const int* __restrict__ col,
    const uint4* __restrict__ H4, const float* __restrict__ as_, const float* __restrict__ ad_,
    const float* __restrict__ bias, const float* __restrict__ Wout, const float* __restrict__ bout,
    float* __restrict__ out, int n)
{
  __shared__ int dg[32], prm[32];
  int lane = threadIdx.x & 63, w = threadIdx.x >> 6;
  int m = lane >> 3, c8 = lane & 7;
  int base = blockIdx.x * 32;
  DEGSORT32(offs2, base, n, dg, prm)
  int sl = prm[w * 8 + m];
  int node0 = base + sl;
  bool ok = node0 < n;
  int node = ok ? node0 : n - 1;
  float denom; float a[8];
  agg_core(offs2, col, H4, as_, ad_, node, c8, denom, a);
  float inv = 1.f / denom;
  float4 b0 = *(const float4*)&bias[8 * c8];
  float4 b1 = *(const float4*)&bias[8 * c8 + 4];
  float4 w0 = *(const float4*)&Wout[8 * c8];
  float4 w1 = *(const float4*)&Wout[8 * c8 + 4];
  float bb[8] = {b0.x, b0.y, b0.z, b0.w, b1.x, b1.y, b1.z, b1.w};
  float ww[8] = {w0.x, w0.y, w0.z, w0.w, w1.x, w1.y, w1.z, w1.w};
  float p = 0.f;
  #pragma unroll
  for (int i = 0; i < 8; ++i)
    p += elu_fast(fmaf(a[i], inv, bb[i])) * ww[i];
  p += __shfl_xor(p, 1, 64); p += __shfl_xor(p, 2, 64); p += __shfl_xor(p, 4, 64);
  if (c8 == 0 && ok) out[node] = p + bout[0];
}

// ---------------- launch ----------------
extern "C" void kernel_launch(void* const* d_in, const int* in_sizes, int n_in,
                              void* d_out, int out_size, void* d_ws, size_t ws_size,
                              hipStream_t stream)
{
  const float* x    = (const float*)d_in[0];
  const int*   ei   = (const int*)d_in[1];   // int32 [2, E] flat
  const float* W1   = (const float*)d_in[2];
  const float* as1w = (const float*)d_in[3];
  const float* ad1w = (const float*)d_in[4];
  const float* b1   = (const float*)d_in[5];
  const float* W2   = (const float*)d_in[6];
  const float* as2w = (const float*)d_in[7];
  const float* ad2w = (const float*)d_in[8];
  const float* b2   = (const float*)d_in[9];
  const float* Wout = (const float*)d_in[10];
  const float* bout = (const float*)d_in[11];
  float* out = (float*)d_out;

  const int N = in_sizes[0] / 128;
  const int E = in_sizes[1] / 2;
  const int* srcA = ei;
  const int* dstA = ei + E;
  const int B   = (N + BKT_NODES - 1) >> BKT_SHIFT;   // 391 buckets; src < 2^17 required
  const int NCH = (E + P1_CHUNK - 1) / P1_CHUNK;      // 391 chunks (must be <= 512 for p2 scan)

  char* p = (char*)d_ws;
  auto alloc = [&](size_t bytes){ char* r = p; p += (bytes + 255) & ~255ull; return r; };
  int2*  offs2  = (int2*)alloc((size_t)N * 8);
  int*   col    = (int*)alloc((size_t)B * BKT_FCAP * 4);       // padded CSR col (9.6 MB)
  int*   offsT  = (int*)alloc((size_t)NCH * (B + 1) * 4);      // per-chunk bucket offsets (613 KB)
  float* vas1 = (float*)alloc((size_t)N * 4);
  float* vad1 = (float*)alloc((size_t)N * 4);
  float* vas2 = (float*)alloc((size_t)N * 4);
  float* vad2 = (float*)alloc((size_t)N * 4);
  uint4* w1f  = (uint4*)alloc(16 * 64 * 16);
  uint4* w2f  = (uint4*)alloc(8 * 64 * 16);
  uint2* h1   = (uint2*)alloc((size_t)N * 64 * 2);   // fp16 [N,64] (layer-1 features)
  uint2* h2   = (uint2*)alloc((size_t)N * 64 * 2);   // fp16 [N,64] (layer-2 features)
  // pairs aliases h2 (NOT h1): p2 reads pairs while mgemm1 writes h1 concurrently;
  // h2 is first written by k_agg1f, after pairs is dead. (6.4 MB <= 12.8 MB)
  unsigned* pairs = (unsigned*)h2;

  k_p1<<<NCH, 512, 0, stream>>>(srcA, dstA, E, B, pairs, offsT, W1, W2, w1f, w2f);

  int gblocks = (N + 63) / 64;
  int ablocks = (N + 31) / 32;
  // p2 (CSR finalize) || mgemm1 (layer-1 GEMM) — independent, complementary pipes
  k_fused<<<B + gblocks, 256, 0, stream>>>(pairs, offsT, NCH, B, N, offs2, col,
                                           x, w1f, as1w, ad1w, h1, vas1, vad1);
  k_agg1f <<<ablocks, 256, 0, stream>>>(offs2, col, (const uint4*)h1, vas1, vad1, b1,
                                        w2f, as2w, ad2w, h2, vas2, vad2, N);
  k_agg2  <<<ablocks, 256, 0, stream>>>(offs2, col, (const uint4*)h2, vas2, vad2, b2, Wout, bout, out, N);
}

// Round 11
// 214.912 us; speedup vs baseline: 1.3694x; 1.0095x over previous
//
#include <hip/hip_runtime.h>
#include <hip/hip_fp16.h>
#include <math.h>

#define NEG_SLOPE 0.2f
#define BKT_SHIFT 8
#define BKT_NODES (1 << BKT_SHIFT)       // 256 nodes per bucket
#define BKT_FCAP 6144                    // fixed col capacity per bucket (avg 4092, 32-sigma)
#define P1_CHUNK 4096                    // edges per p1 block (block-owned region)
#define SEG_SHIFT 14                     // src segments of 16384 nodes

typedef _Float16 f16x8 __attribute__((ext_vector_type(8)));
typedef float    f32x4 __attribute__((ext_vector_type(4)));
union FU  { uint4 u; f16x8 f; };
union H2U { __half2 h; unsigned u; };

__device__ __forceinline__ float lrelu(float x){ return fmaxf(x, NEG_SLOPE * x); }
__device__ __forceinline__ float elu_fast(float x){
  float t = __expf(fminf(x, 0.f)) - 1.f;
  return x > 0.f ? x : t;
}

// ---------------- p1: block-owned counting sort of 4096 edges ----------------
__global__ __launch_bounds__(512) void k_p1(const int* __restrict__ src, const int* __restrict__ dst,
                                            int E, int B,
                                            unsigned* __restrict__ pairs, int* __restrict__ offsT,
                                            const float* __restrict__ W1, const float* __restrict__ W2,
                                            uint4* __restrict__ W1f, uint4* __restrict__ W2f){
  __shared__ int h[512], cur[512];
  __shared__ unsigned stage[P1_CHUNK];
  int tid = threadIdx.x;
  if (blockIdx.x == 0){
    for (int idx = tid; idx < 16 * 64; idx += 512){
      int lane = idx & 63, fs = idx >> 6;
      int t = fs >> 2, s = fs & 3;
      int m = lane & 15, quad = lane >> 4;
      f16x8 v;
      #pragma unroll
      for (int j = 0; j < 8; ++j)
        v[j] = (_Float16)W1[(s * 32 + quad * 8 + j) * 64 + t * 16 + m];
      FU fu; fu.f = v;
      W1f[fs * 64 + lane] = fu.u;
    }
    for (int idx = tid; idx < 8 * 64; idx += 512){
      int lane = idx & 63, fs = idx >> 6;
      int t = fs >> 1, s = fs & 1;
      int m = lane & 15, quad = lane >> 4;
      f16x8 v;
      #pragma unroll
      for (int j = 0; j < 8; ++j)
        v[j] = (_Float16)W2[(s * 32 + quad * 8 + j) * 64 + t * 16 + m];
      FU fu; fu.f = v;
      W2f[fs * 64 + lane] = fu.u;
    }
  }
  h[tid] = 0;
  __syncthreads();
  int beg = blockIdx.x * P1_CHUNK;
  int end = min(beg + P1_CHUNK, E);
  int cnt = end - beg;
  int m4 = cnt >> 2;
  const int4* d4 = (const int4*)(dst + beg);
  const int4* s4 = (const int4*)(src + beg);
  for (int i = tid; i < m4; i += 512){
    int4 d = d4[i];
    atomicAdd(&h[d.x >> BKT_SHIFT], 1); atomicAdd(&h[d.y >> BKT_SHIFT], 1);
    atomicAdd(&h[d.z >> BKT_SHIFT], 1); atomicAdd(&h[d.w >> BKT_SHIFT], 1);
  }
  for (int i = (m4 << 2) + tid; i < cnt; i += 512)
    atomicAdd(&h[dst[beg + i] >> BKT_SHIFT], 1);
  __syncthreads();
  int v = h[tid];
  for (int o = 1; o < 512; o <<= 1){
    int x = (tid >= o) ? h[tid - o] : 0;
    __syncthreads();
    h[tid] += x;
    __syncthreads();
  }
  int e = h[tid] - v;
  cur[tid] = e;
  int* orow = offsT + (size_t)blockIdx.x * (B + 1);
  if (tid <= B) orow[tid] = e;
  __syncthreads();
  for (int i = tid; i < m4; i += 512){
    int4 d = d4[i]; int4 s = s4[i];
    int p0 = atomicAdd(&cur[d.x >> BKT_SHIFT], 1);
    stage[p0] = ((unsigned)(d.x & (BKT_NODES-1)) << 17) | (unsigned)s.x;
    int p1 = atomicAdd(&cur[d.y >> BKT_SHIFT], 1);
    stage[p1] = ((unsigned)(d.y & (BKT_NODES-1)) << 17) | (unsigned)s.y;
    int p2 = atomicAdd(&cur[d.z >> BKT_SHIFT], 1);
    stage[p2] = ((unsigned)(d.z & (BKT_NODES-1)) << 17) | (unsigned)s.z;
    int p3 = atomicAdd(&cur[d.w >> BKT_SHIFT], 1);
    stage[p3] = ((unsigned)(d.w & (BKT_NODES-1)) << 17) | (unsigned)s.w;
  }
  for (int i = (m4 << 2) + tid; i < cnt; i += 512){
    int d = dst[beg + i], s = src[beg + i];
    int p = atomicAdd(&cur[d >> BKT_SHIFT], 1);
    stage[p] = ((unsigned)(d & (BKT_NODES-1)) << 17) | (unsigned)s;
  }
  __syncthreads();
  unsigned* prow = pairs + (size_t)blockIdx.x * P1_CHUNK;
  for (int i = tid; i < cnt; i += 512) prow[i] = stage[i];
}

// ---------------- p2: per-bucket CSR finalize (2048-bin node x segment sort) ----------------
__device__ __forceinline__ void p2_body(const unsigned* __restrict__ pairs,
                                        const int* __restrict__ offsT,
                                        int NCH, int B, int N,
                                        int2* __restrict__ offs2, int* __restrict__ col, int b){
  __shared__ int rbase[512], scant[256];
  __shared__ int sc2[2048];
  __shared__ unsigned estage[BKT_FCAP];
  int tid = threadIdx.x;
  int nbase = b << BKT_SHIFT;
  int bs = b * BKT_FCAP;
  int i0 = tid, i1 = tid + 256;
  int st0 = 0, ln0 = 0, st1 = 0, ln1 = 0;
  if (i0 < NCH){ int o = offsT[(size_t)i0 * (B + 1) + b]; st0 = o; ln0 = offsT[(size_t)i0 * (B + 1) + b + 1] - o; }
  if (i1 < NCH){ int o = offsT[(size_t)i1 * (B + 1) + b]; st1 = o; ln1 = offsT[(size_t)i1 * (B + 1) + b + 1] - o; }
  rbase[tid] = ln0; rbase[tid + 256] = ln1;
  #pragma unroll
  for (int k = 0; k < 8; ++k) sc2[tid * 8 + k] = 0;
  __syncthreads();
  for (int o = 1; o < 512; o <<= 1){
    int x0 = (tid >= o) ? rbase[tid - o] : 0;
    int x1 = rbase[tid + 256 - o];
    __syncthreads();
    rbase[tid] += x0; rbase[tid + 256] += x1;
    __syncthreads();
  }
  int tot = rbase[511];
  int r0 = rbase[tid] - ln0, r1 = rbase[tid + 256] - ln1;
  for (int j = 0; j < ln0; ++j) estage[r0 + j] = pairs[(size_t)i0 * P1_CHUNK + st0 + j];
  for (int j = 0; j < ln1; ++j) estage[r1 + j] = pairs[(size_t)i1 * P1_CHUNK + st1 + j];
  __syncthreads();
  for (int i = tid; i < tot; i += 256){
    unsigned pr = estage[i];
    int key = (int)(pr >> 17) * 8 + (int)((pr & 0x1FFFFu) >> SEG_SHIFT);
    atomicAdd(&sc2[key], 1);
  }
  __syncthreads();
  int loc[8]; int s = 0;
  #pragma unroll
  for (int k = 0; k < 8; ++k){ loc[k] = sc2[tid * 8 + k]; s += loc[k]; }
  scant[tid] = s;
  __syncthreads();
  for (int o = 1; o < 256; o <<= 1){
    int x = (tid >= o) ? scant[tid - o] : 0;
    __syncthreads();
    scant[tid] += x;
    __syncthreads();
  }
  int ex = scant[tid] - s;
  if (nbase + tid < N) offs2[nbase + tid] = make_int2(bs + ex, bs + ex + s);
  int run = bs + ex;
  #pragma unroll
  for (int k = 0; k < 8; ++k){ int c = loc[k]; sc2[tid * 8 + k] = run; run += c; }
  __syncthreads();
  for (int i = tid; i < tot; i += 256){
    unsigned pr = estage[i];
    int key = (int)(pr >> 17) * 8 + (int)((pr & 0x1FFFFu) >> SEG_SHIFT);
    int p = atomicAdd(&sc2[key], 1);
    col[p] = (int)(pr & 0x1FFFFu);
  }
}

// ---------------- MFMA GEMM 1 body ----------------
__device__ __forceinline__ void mg1_body(
    const float* __restrict__ X, const uint4* __restrict__ Wf,
    const float* __restrict__ a_src, const float* __restrict__ a_dst,
    uint2* __restrict__ H, float* __restrict__ as_, float* __restrict__ ad_, int n, int bb)
{
  int lane = threadIdx.x & 63, wv = threadIdx.x >> 6;
  int quad = lane >> 4, nn = lane & 15;
  int rowb = bb * 64 + wv * 16;
  int row = rowb + nn;
  bool ok = row < n;
  int rowc = ok ? row : n - 1;

  f16x8 af[4][4];
  #pragma unroll
  for (int t = 0; t < 4; ++t)
    #pragma unroll
    for (int s = 0; s < 4; ++s){
      FU fu; fu.u = Wf[(t * 4 + s) * 64 + lane];
      af[t][s] = fu.f;
    }

  const float4* Xr = (const float4*)(X + (size_t)rowc * 128);
  float4 xb[4][2];
  #pragma unroll
  for (int s = 0; s < 4; ++s){
    xb[s][0] = Xr[s * 8 + quad * 2];
    xb[s][1] = Xr[s * 8 + quad * 2 + 1];
  }

  f32x4 acc[4] = {};
  #pragma unroll
  for (int s = 0; s < 4; ++s){
    f16x8 bf;
    bf[0] = (_Float16)xb[s][0].x; bf[1] = (_Float16)xb[s][0].y;
    bf[2] = (_Float16)xb[s][0].z; bf[3] = (_Float16)xb[s][0].w;
    bf[4] = (_Float16)xb[s][1].x; bf[5] = (_Float16)xb[s][1].y;
    bf[6] = (_Float16)xb[s][1].z; bf[7] = (_Float16)xb[s][1].w;
    #pragma unroll
    for (int t = 0; t < 4; ++t)
      acc[t] = __builtin_amdgcn_mfma_f32_16x16x32_f16(af[t][s], bf, acc[t], 0, 0, 0);
  }

  if (ok){
    #pragma unroll
    for (int t = 0; t < 4; ++t){
      H2U p0, p1;
      p0.h = __floats2half2_rn(acc[t][0], acc[t][1]);
      p1.h = __floats2half2_rn(acc[t][2], acc[t][3]);
      H[(size_t)row * 16 + t * 4 + quad] = make_uint2(p0.u, p1.u);
    }
  }
  float sl = 0.f, dl = 0.f;
  #pragma unroll
  for (int t = 0; t < 4; ++t){
    float4 a4 = ((const float4*)a_src)[t * 4 + quad];
    float4 d4 = ((const float4*)a_dst)[t * 4 + quad];
    sl += acc[t][0] * a4.x + acc[t][1] * a4.y + acc[t][2] * a4.z + acc[t][3] * a4.w;
    dl += acc[t][0] * d4.x + acc[t][1] * d4.y + acc[t][2] * d4.z + acc[t][3] * d4.w;
  }
  sl += __shfl_xor(sl, 16, 64); sl += __shfl_xor(sl, 32, 64);
  dl += __shfl_xor(dl, 16, 64); dl += __shfl_xor(dl, 32, 64);
  if (lane < 16 && ok){ as_[row] = sl; ad_[row] = dl; }
}

__global__ __launch_bounds__(256) void k_fused(
    const unsigned* __restrict__ pairs, const int* __restrict__ offsT,
    int NCH, int B, int N, int2* __restrict__ offs2, int* __restrict__ col,
    const float* __restrict__ X, const uint4* __restrict__ Wf,
    const float* __restrict__ a_src, const float* __restrict__ a_dst,
    uint2* __restrict__ H, float* __restrict__ as_, float* __restrict__ ad_)
{
  if ((int)blockIdx.x < B)
    p2_body(pairs, offsT, NCH, B, N, offs2, col, blockIdx.x);
  else
    mg1_body(X, Wf, a_src, a_dst, H, as_, ad_, N, blockIdx.x - B);
}

// ---------------- attention aggregation core (round-0 proven) ----------------
#define FMA8(e, hv) { const __half2* hp = (const __half2*)&(hv);               \
  a[0]=fmaf(e, __half2float(hp[0].x), a[0]); a[1]=fmaf(e, __half2float(hp[0].y), a[1]); \
  a[2]=fmaf(e, __half2float(hp[1].x), a[2]); a[3]=fmaf(e, __half2float(hp[1].y), a[3]); \
  a[4]=fmaf(e, __half2float(hp[2].x), a[4]); a[5]=fmaf(e, __half2float(hp[2].y), a[5]); \
  a[6]=fmaf(e, __half2float(hp[3].x), a[6]); a[7]=fmaf(e, __half2float(hp[3].y), a[7]); }

__device__ __forceinline__ void agg_core(
    const int2* __restrict__ offs2, const int* __restrict__ col,
    const uint4* __restrict__ H4, const float* __restrict__ as_, const float* __restrict__ ad_,
    int node, int c8, float& denom, float a[8])
{
  int2 be2 = offs2[node];
  int beg = be2.x, d = be2.y - be2.x;
  int maxd = d;
  maxd = max(maxd, __shfl_xor(maxd, 8, 64));
  maxd = max(maxd, __shfl_xor(maxd, 16, 64));
  maxd = max(maxd, __shfl_xor(maxd, 32, 64));
  float adv = ad_[node];
  float exs = __expf(lrelu(as_[node] + adv));
  uint4 hself = H4[(size_t)node * 8 + c8];
  denom = exs;
  { const __half2* hp = (const __half2*)&hself;
    #pragma unroll
    for (int i = 0; i < 4; ++i){
      a[2*i]   = exs * __half2float(hp[i].x);
      a[2*i+1] = exs * __half2float(hp[i].y);
    } }
  for (int j = 0; j < maxd; j += 4){
    int ss[4]; float asv[4]; uint4 hv[4];
    #pragma unroll
    for (int u = 0; u < 4; ++u) ss[u] = (j + u < d) ? col[beg + j + u] : 0;
    #pragma unroll
    for (int u = 0; u < 4; ++u) asv[u] = as_[ss[u]];
    #pragma unroll
    for (int u = 0; u < 4; ++u) hv[u] = H4[(size_t)ss[u] * 8 + c8];
    #pragma unroll
    for (int u = 0; u < 4; ++u){
      float e = (j + u < d) ? __expf(lrelu(asv[u] + adv)) : 0.f;
      denom += e;
      FMA8(e, hv[u])
    }
  }
}

// block-local degree-balanced assignment over 16 nodes (2 waves x 8): rank-sort
// so each wave's 8 nodes have similar degree. Zero locality change.
#define DEGSORT16(offs2, base, n, dg, prm)                                     \
  { int tid_ = threadIdx.x;                                                    \
    if (tid_ < 16){                                                            \
      int nd_ = min(base + tid_, n - 1);                                       \
      int2 be_ = offs2[nd_];                                                   \
      dg[tid_] = be_.y - be_.x;                                                \
    }                                                                          \
    __syncthreads();                                                           \
    if (tid_ < 16){                                                            \
      int d_ = dg[tid_]; int r_ = 0;                                           \
      _Pragma("unroll")                                                        \
      for (int j_ = 0; j_ < 16; ++j_){                                         \
        int dj_ = dg[j_];                                                      \
        r_ += (dj_ < d_) || (dj_ == d_ && j_ < tid_);                          \
      }                                                                        \
      prm[r_] = tid_;                                                          \
    }                                                                          \
    __syncthreads(); }

// ---------------- fused agg1 + GEMM2: one block = 16 nodes (128 thr, 2 waves) ----------
// Finer blocks pack the CU wave slots better (16 wg/CU x 2 waves = full 32-wave ceiling;
// backfill granularity halves; barrier couples 2 waves not 4).
__global__ __launch_bounds__(128) void k_agg1f(
    const int2* __restrict__ offs2, const int* __restrict__ col,
    const uint4* __restrict__ H4, const float* __restrict__ as_, const float* __restrict__ ad_,
    const float* __restrict__ bias, const uint4* __restrict__ W2f,
    const float* __restrict__ a_src2, const float* __restrict__ a_dst2,
    uint2* __restrict__ H2out, float* __restrict__ as2_, float* __restrict__ ad2_, int n)
{
  // 72 halves/row (36 uints, 144 B stride): breaks the 128 B power-of-2 bank pattern
  __shared__ unsigned uhl[16][36];
  __shared__ int dg[16], prm[16];
  int lane = threadIdx.x & 63, w = threadIdx.x >> 6;   // w in {0,1}
  int m = lane >> 3, c8 = lane & 7;
  int base = blockIdx.x * 16;
  DEGSORT16(offs2, base, n, dg, prm)
  int sl = prm[w * 8 + m];          // local node index (degree-balanced assignment)
  int node0 = base + sl;
  bool ok = node0 < n;
  int node = ok ? node0 : n - 1;
  float denom; float a[8];
  agg_core(offs2, col, H4, as_, ad_, node, c8, denom, a);
  float inv = 1.f / denom;
  float4 b0 = *(const float4*)&bias[8 * c8];
  float4 b1 = *(const float4*)&bias[8 * c8 + 4];
  float bb[8] = {b0.x, b0.y, b0.z, b0.w, b1.x, b1.y, b1.z, b1.w};
  // uhl indexed by LOCAL NODE index sl (perm is a bijection -> every row written once)
  #pragma unroll
  for (int i = 0; i < 4; ++i){
    float v0 = elu_fast(fmaf(a[2*i],   inv, bb[2*i]));
    float v1 = elu_fast(fmaf(a[2*i+1], inv, bb[2*i+1]));
    __half2 h = __floats2half2_rn(v0, v1);
    uhl[sl][c8 * 4 + i] = *(unsigned*)&h;
  }
  __syncthreads();

  // -------- phase 2: 16-row GEMM on wave 0 (rows nn, positional) --------
  if (w == 0){
    int quad = lane >> 4, nn = lane & 15;
    int lrow = nn;
    int row = base + lrow;
    bool ok2 = row < n;

    f16x8 af[4][2];
    #pragma unroll
    for (int t = 0; t < 4; ++t)
      #pragma unroll
      for (int s = 0; s < 2; ++s){
        FU fu; fu.u = W2f[(t * 2 + s) * 64 + lane];
        af[t][s] = fu.f;
      }

    f16x8 bf[2];
    #pragma unroll
    for (int s = 0; s < 2; ++s){
      FU fu; fu.u = ((const uint4*)&uhl[lrow][0])[s * 4 + quad];
      bf[s] = fu.f;
    }

    f32x4 acc[4] = {};
    #pragma unroll
    for (int s = 0; s < 2; ++s)
      #pragma unroll
      for (int t = 0; t < 4; ++t)
        acc[t] = __builtin_amdgcn_mfma_f32_16x16x32_f16(af[t][s], bf[s], acc[t], 0, 0, 0);

    if (ok2){
      #pragma unroll
      for (int t = 0; t < 4; ++t){
        H2U p0, p1;
        p0.h = __floats2half2_rn(acc[t][0], acc[t][1]);
        p1.h = __floats2half2_rn(acc[t][2], acc[t][3]);
        H2out[(size_t)row * 16 + t * 4 + quad] = make_uint2(p0.u, p1.u);
      }
    }
    float sl2 = 0.f, dl2 = 0.f;
    #pragma unroll
    for (int t = 0; t < 4; ++t){
      float4 a4 = ((const float4*)a_src2)[t * 4 + quad];
      float4 d4 = ((const float4*)a_dst2)[t * 4 + quad];
      sl2 += acc[t][0] * a4.x + acc[t][1] * a4.y + acc[t][2] * a4.z + acc[t][3] * a4.w;
      dl2 += acc[t][0] * d4.x + acc[t][1] * d4.y + acc[t][2] * d4.z + acc[t][3] * d4.w;
    }
    sl2 += __shfl_xor(sl2, 16, 64); sl2 += __shfl_xor(sl2, 32, 64);
    dl2 += __shfl_xor(dl2, 16, 64); dl2 += __shfl_xor(dl2, 32, 64);
    if (lane < 16 && ok2){ as2_[row] = sl2; ad2_[row] = dl2; }
  }
}

// ---------------- agg2: layer-2 aggregation + output head (128 thr, 16 nodes) ------------
__global__ __launch_bounds__(128) void k_agg2(
    const int2* __restrict__ offs2, const int* __restrict__ col,
    const uint4* __restrict__ H4, const float* __restrict__ as_, const float* __restrict__ ad_,
    const float* __restrict__ bias, const float* __restrict__ Wout, const float* __restrict__ bout,
    float* __restrict__ out, int n)
{
  __shared__ int dg[16], prm[16];
  int lane = threadIdx.x & 63, w = threadIdx.x >> 6;
  int m = lane >> 3, c8 = lane & 7;
  int base = blockIdx.x * 16;
  DEGSORT16(offs2, base, n, dg, prm)
  int sl = prm[w * 8 + m];
  int node0 = base + sl;
  bool ok = node0 < n;
  int node = ok ? node0 : n - 1;
  float denom; float a[8];
  agg_core(offs2, col, H4, as_, ad_, node, c8, denom, a);
  float inv = 1.f / denom;
  float4 b0 = *(const float4*)&bias[8 * c8];
  float4 b1 = *(const float4*)&bias[8 * c8 + 4];
  float4 w0 = *(const float4*)&Wout[8 * c8];
  float4 w1 = *(const float4*)&Wout[8 * c8 + 4];
  float bb[8] = {b0.x, b0.y, b0.z, b0.w, b1.x, b1.y, b1.z, b1.w};
  float ww[8] = {w0.x, w0.y, w0.z, w0.w, w1.x, w1.y, w1.z, w1.w};
  float p = 0.f;
  #pragma unroll
  for (int i = 0; i < 8; ++i)
    p += elu_fast(fmaf(a[i], inv, bb[i])) * ww[i];
  p += __shfl_xor(p, 1, 64); p += __shfl_xor(p, 2, 64); p += __shfl_xor(p, 4, 64);
  if (c8 == 0 && ok) out[node] = p + bout[0];
}

// ---------------- launch ----------------
extern "C" void kernel_launch(void* const* d_in, const int* in_sizes, int n_in,
                              void* d_out, int out_size, void* d_ws, size_t ws_size,
                              hipStream_t stream)
{
  const float* x    = (const float*)d_in[0];
  const int*   ei   = (const int*)d_in[1];   // int32 [2, E] flat
  const float* W1   = (const float*)d_in[2];
  const float* as1w = (const float*)d_in[3];
  const float* ad1w = (const float*)d_in[4];
  const float* b1   = (const float*)d_in[5];
  const float* W2   = (const float*)d_in[6];
  const float* as2w = (const float*)d_in[7];
  const float* ad2w = (const float*)d_in[8];
  const float* b2   = (const float*)d_in[9];
  const float* Wout = (const float*)d_in[10];
  const float* bout = (const float*)d_in[11];
  float* out = (float*)d_out;

  const int N = in_sizes[0] / 128;
  const int E = in_sizes[1] / 2;
  const int* srcA = ei;
  const int* dstA = ei + E;
  const int B   = (N + BKT_NODES - 1) >> BKT_SHIFT;   // 391 buckets; src < 2^17 required
  const int NCH = (E + P1_CHUNK - 1) / P1_CHUNK;      // 391 chunks (must be <= 512 for p2 scan)

  char* p = (char*)d_ws;
  auto alloc = [&](size_t bytes){ char* r = p; p += (bytes + 255) & ~255ull; return r; };
  int2*  offs2  = (int2*)alloc((size_t)N * 8);
  int*   col    = (int*)alloc((size_t)B * BKT_FCAP * 4);       // padded CSR col (9.6 MB)
  int*   offsT  = (int*)alloc((size_t)NCH * (B + 1) * 4);      // per-chunk bucket offsets (613 KB)
  float* vas1 = (float*)alloc((size_t)N * 4);
  float* vad1 = (float*)alloc((size_t)N * 4);
  float* vas2 = (float*)alloc((size_t)N * 4);
  float* vad2 = (float*)alloc((size_t)N * 4);
  uint4* w1f  = (uint4*)alloc(16 * 64 * 16);
  uint4* w2f  = (uint4*)alloc(8 * 64 * 16);
  uint2* h1   = (uint2*)alloc((size_t)N * 64 * 2);   // fp16 [N,64] (layer-1 features)
  uint2* h2   = (uint2*)alloc((size_t)N * 64 * 2);   // fp16 [N,64] (layer-2 features)
  // pairs aliases h2 (NOT h1): p2 reads pairs while mgemm1 writes h1 concurrently;
  // h2 is first written by k_agg1f, after pairs is dead. (6.4 MB <= 12.8 MB)
  unsigned* pairs = (unsigned*)h2;

  k_p1<<<NCH, 512, 0, stream>>>(srcA, dstA, E, B, pairs, offsT, W1, W2, w1f, w2f);

  int gblocks = (N + 63) / 64;
  int ablocks = (N + 15) / 16;   // 16 nodes per 128-thread block
  // p2 (CSR finalize) || mgemm1 (layer-1 GEMM) — independent, complementary pipes
  k_fused<<<B + gblocks, 256, 0, stream>>>(pairs, offsT, NCH, B, N, offs2, col,
                                           x, w1f, as1w, ad1w, h1, vas1, vad1);
  k_agg1f <<<ablocks, 128, 0, stream>>>(offs2, col, (const uint4*)h1, vas1, vad1, b1,
                                        w2f, as2w, ad2w, h2, vas2, vad2, N);
  k_agg2  <<<ablocks, 128, 0, stream>>>(offs2, col, (const uint4*)h2, vas2, vad2, b2, Wout, bout, out, N);
}